// Round 5
// baseline (153.643 us; speedup 1.0000x reference)
//
#include <hip/hip_runtime.h>
#include <hip/hip_bf16.h>

// ---------------------------------------------------------------------------
// Sliding-window attention (B=4,S=2048,D=1024,H=16,HD=64,W=256) on gfx950.
// Pipeline: cvt(f32->bf16) -> GEMM(QKV, 256x192 cluster-pipelined) ->
//           RoPE+reshape (+permuted V^T) -> flash window attention ->
//           GEMM(O-proj, 256x128 cluster-pipelined).
// ---------------------------------------------------------------------------

typedef __bf16 bf16_t;
typedef __attribute__((ext_vector_type(8))) __bf16 bf16x8;
typedef __attribute__((ext_vector_type(4))) __bf16 bf16x4;
typedef __attribute__((ext_vector_type(4))) float f32x4;

#define MFMA16(a, b, c) __builtin_amdgcn_mfma_f32_16x16x32_bf16((a), (b), (c), 0, 0, 0)

// async global->LDS, 16 bytes per lane. LDS dest is wave-uniform base + lane*16.
__device__ __forceinline__ void async16(const void* g, void* l) {
    __builtin_amdgcn_global_load_lds(
        (const __attribute__((address_space(1))) unsigned int*)g,
        (__attribute__((address_space(3))) unsigned int*)l, 16, 0, 0);
}

#define BAR() do { asm volatile("" ::: "memory"); __builtin_amdgcn_s_barrier(); \
                   asm volatile("" ::: "memory"); } while (0)
#define VMC(N) asm volatile("s_waitcnt vmcnt(" #N ")" ::: "memory")

// ---------------------------------------------------------------------------
// f32 -> bf16 convert, 8 elems/thread
// ---------------------------------------------------------------------------
__global__ __launch_bounds__(256) void cvt_kernel(const float* __restrict__ s,
                                                  bf16_t* __restrict__ d, int n) {
    int i = (blockIdx.x * 256 + threadIdx.x) * 8;
    if (i >= n) return;
    float4 a = *(const float4*)(s + i);
    float4 b = *(const float4*)(s + i + 4);
    bf16x8 o;
    o[0] = (bf16_t)a.x; o[1] = (bf16_t)a.y; o[2] = (bf16_t)a.z; o[3] = (bf16_t)a.w;
    o[4] = (bf16_t)b.x; o[5] = (bf16_t)b.y; o[6] = (bf16_t)b.z; o[7] = (bf16_t)b.w;
    *(bf16x8*)(d + i) = o;
}

// ---------------------------------------------------------------------------
// 256x192 cluster-pipelined GEMM: C[M][N] = A[M][K] @ Bw[N][K]^T.
// 512 threads = 8 waves (2M x 4N); per-wave C = 128x48 (acc = 96, in AGPR).
// BK=64.  LDS 112 KiB: A = 2buf x 4units, B = 2buf x 3units; unit = 64x64
// = 8 KiB staged by ONE gload_lds/thread; st_16x32 XOR swizzle, linear LDS
// dest + inverse-swizzled global source + swizzled ds_read.
//
// R5 schedule (the R4 fix): intra-tile barriers REMOVED. Per tile, 4 MFMA
// clusters (mh,ks) of 12; each cluster's ds_reads are issued BEFORE the
// previous cluster's MFMA, so the LDS pipe drains reads while the matrix
// pipes run (compiler inserts counted lgkmcnt per data-dep).  ONE
// VMC(0)+BAR per tile:
//   - certifies tile t+1 (its 7 stages were issued at the TOP of tile t's
//     body, ~a full tile (~2000cy) before the drain -> HBM latency covered)
//   - fences buffer reuse: stage(t+1) targets buf(t-1); every wave's reads
//     of t-1 completed (lgkm before its last MFMA) before it arrived at the
//     previous barrier, and no wave passes that barrier early.
// ---------------------------------------------------------------------------
template <typename OUT>
__global__ __launch_bounds__(512, 1) __attribute__((amdgpu_waves_per_eu(2)))
void gemm192(const bf16_t* __restrict__ A, const bf16_t* __restrict__ Bw,
             OUT* __restrict__ C, int M, int N, int K) {
    __shared__ __attribute__((aligned(16))) bf16_t As[32768];   // 2 x 4u x 8KiB
    __shared__ __attribute__((aligned(16))) bf16_t Bs[24576];   // 2 x 3u x 8KiB
    const int tid = threadIdx.x;
    const int l = tid & 63, w = tid >> 6;
    const int lr = l & 15, lg = l >> 4;
    const int wr = w >> 2, wc = w & 3;          // 2M x 4N

    const int nwg = gridDim.x * gridDim.y;
    const int flat = blockIdx.y * gridDim.x + blockIdx.x;
    const int swz = (flat & 7) * (nwg >> 3) + (flat >> 3);
    const int bx = swz % gridDim.x, by = swz / gridDim.x;
    const long m0 = (long)by * 256, n0 = (long)bx * 192;
    const int NT = K >> 6;       // 64-wide K tiles (>= 2)

    // staging decode (8 KiB unit = 64 rows x 64 cols, 1 load/thread):
    // linear LDS byte p -> unswizzle -> (row, col) -> global source.
    const int p  = w * 1024 + l * 16;
    const int pp = p ^ (((p >> 9) & 1) << 5);
    const int st = pp >> 10;                         // 1 KiB subtile 0..7
    const int rSt = (st >> 1) * 16 + ((pp >> 6) & 15);
    const int cSt = (st & 1) * 32 + ((pp >> 4) & 3) * 8;
    const bf16_t* aS = A  + (m0 + rSt) * K + cSt;
    const bf16_t* bS = Bw + (n0 + rSt) * K + cSt;
    const long uK = 64L * K;                         // unit row stride

    auto stageA = [&](int b, int u, int t) {
        async16(aS + (long)u * uK + (long)t * 64,
                (char*)As + b * 32768 + u * 8192 + w * 1024);
    };
    auto stageB = [&](int b, int u, int t) {
        async16(bS + (long)u * uK + (long)t * 64,
                (char*)Bs + b * 24576 + u * 8192 + w * 1024);
    };

    f32x4 acc[8][3] = {};
    bf16x8 afX[4], afY[4], bfX[3], bfY[3];
    const int swd = (lr & 8) << 2;    // ds_read swizzle: byte bit5 ^= row bit3

    auto loadAF = [&](int b, int mh, int ks, bf16x8 (&dst)[4]) {
#pragma unroll
        for (int mi = 0; mi < 4; ++mi) {
            const int off = (wr * 2 + mh) * 8192 + (mi * 2 + ks) * 1024 +
                            lr * 64 + lg * 16;
            dst[mi] = *(const bf16x8*)((const char*)As + b * 32768 + (off ^ swd));
        }
    };
    auto loadBF = [&](int b, int ks, bf16x8 (&dst)[3]) {
#pragma unroll
        for (int nj = 0; nj < 3; ++nj) {
            const int rg = wc * 48 + nj * 16 + lr;           // N-row 0..191
            const int off = (rg >> 6) * 8192 + (((rg >> 4) & 3) * 2 + ks) * 1024 +
                            lr * 64 + lg * 16;
            dst[nj] = *(const bf16x8*)((const char*)Bs + b * 24576 + (off ^ swd));
        }
    };

#define QMM(MH, AF, BF) do {                                                   \
    __builtin_amdgcn_s_setprio(1);                                             \
    _Pragma("unroll")                                                          \
    for (int mi = 0; mi < 4; ++mi)                                             \
        _Pragma("unroll")                                                      \
        for (int nj = 0; nj < 3; ++nj)                                         \
            acc[(MH)*4+mi][nj] = MFMA16((AF)[mi], (BF)[nj], acc[(MH)*4+mi][nj]); \
    __builtin_amdgcn_s_setprio(0);                                             \
} while (0)

    // ---- prologue: stage tile 0, certify (one-time cold stall) ----
    stageA(0, 0, 0); stageA(0, 1, 0); stageA(0, 2, 0); stageA(0, 3, 0);
    stageB(0, 0, 0); stageB(0, 1, 0); stageB(0, 2, 0);
    VMC(0); BAR();

#pragma unroll 1
    for (int t = 0; t < NT - 1; ++t) {
        const int bc = t & 1, bn = bc ^ 1;
        // cluster-0 reads (mh0,ks0 + B ks0) -- the only exposed read burst
        loadAF(bc, 0, 0, afX); loadBF(bc, 0, bfX);
        // stage tile t+1 early (into buf of t-1, freed by last barrier)
        stageA(bn, 0, t + 1); stageA(bn, 1, t + 1);
        stageA(bn, 2, t + 1); stageA(bn, 3, t + 1);
        stageB(bn, 0, t + 1); stageB(bn, 1, t + 1); stageB(bn, 2, t + 1);
        // pipelined clusters: issue next cluster's reads, then MFMA current
        loadAF(bc, 1, 0, afY);
        QMM(0, afX, bfX);
        loadAF(bc, 0, 1, afX); loadBF(bc, 1, bfY);
        QMM(1, afY, bfX);
        loadAF(bc, 1, 1, afY);
        QMM(0, afX, bfY);
        QMM(1, afY, bfY);
        // certify tile t+1; fence buffer reuse
        VMC(0); BAR();
    }
    // ---- last tile: resident, no stages, no barriers ----
    {
        const int bc = (NT - 1) & 1;
        loadAF(bc, 0, 0, afX); loadBF(bc, 0, bfX);
        loadAF(bc, 1, 0, afY);
        QMM(0, afX, bfX);
        loadAF(bc, 0, 1, afX); loadBF(bc, 1, bfY);
        QMM(1, afY, bfX);
        loadAF(bc, 1, 1, afY);
        QMM(0, afX, bfY);
        QMM(1, afY, bfY);
    }
#undef QMM

    // ---- epilogue: fragment row = lg*4+j, col = lr ----
#pragma unroll
    for (int ai = 0; ai < 8; ++ai)
#pragma unroll
        for (int nj = 0; nj < 3; ++nj)
#pragma unroll
            for (int j = 0; j < 4; ++j) {
                long r = m0 + wr * 128 + ai * 16 + lg * 4 + j;
                long c = n0 + wc * 48 + nj * 16 + lr;
                C[r * (long)N + c] = (OUT)acc[ai][nj][j];
            }
}

// ---------------------------------------------------------------------------
// 256x128 cluster-pipelined GEMM (O-proj: N=1024 -> 256 blocks = 1 round).
// Same R5 schedule: 2 LDS buffers (96 KiB), 2 clusters of 16 MFMA, one
// VMC(0)+BAR per tile, stages issued at tile top.
// ---------------------------------------------------------------------------
template <typename OUT>
__global__ __launch_bounds__(512, 2) void gemm256(const bf16_t* __restrict__ A,
                                                  const bf16_t* __restrict__ Bw,
                                                  OUT* __restrict__ C,
                                                  int M, int N, int K) {
    __shared__ __attribute__((aligned(16))) bf16_t As[32768];   // 2 x 2 x 128x64
    __shared__ __attribute__((aligned(16))) bf16_t Bs[16384];   // 2 x 128x64
    const int tid = threadIdx.x;
    const int l = tid & 63, w = tid >> 6;
    const int lr = l & 15, lg = l >> 4;
    const int wr = w >> 1, wc = w & 1;

    const int nwg = gridDim.x * gridDim.y;
    const int flat = blockIdx.y * gridDim.x + blockIdx.x;
    const int swz = (flat & 7) * (nwg >> 3) + (flat >> 3);
    const int bx = swz % gridDim.x, by = swz / gridDim.x;
    const long m0 = (long)by * 256, n0 = (long)bx * 128;
    const int NT = K >> 6;

    int rS[2], cS[2];
#pragma unroll
    for (int i = 0; i < 2; ++i) {
        const int p  = i * 8192 + w * 1024 + l * 16;
        const int pp = p ^ (((p >> 9) & 1) << 5);
        const int st = pp >> 10;
        rS[i] = (st >> 1) * 16 + ((pp >> 6) & 15);
        cS[i] = (st & 1) * 32 + ((pp >> 4) & 3) * 8;
    }
    const bf16_t* aSrc0 = A  + (m0 + rS[0]) * K + cS[0];
    const bf16_t* aSrc1 = A  + (m0 + rS[1]) * K + cS[1];
    const bf16_t* bSrc0 = Bw + (n0 + rS[0]) * K + cS[0];
    const bf16_t* bSrc1 = Bw + (n0 + rS[1]) * K + cS[1];
    const long hK = 128L * K;

    auto stageA = [&](int b, int h, int t) {
        char* d = (char*)As + b * 32768 + h * 16384 + w * 1024;
        const long o = (long)h * hK + (long)t * 64;
        async16(aSrc0 + o, d);
        async16(aSrc1 + o, d + 8192);
    };
    auto stageB = [&](int b, int t) {
        char* d = (char*)Bs + b * 16384 + w * 1024;
        const long o = (long)t * 64;
        async16(bSrc0 + o, d);
        async16(bSrc1 + o, d + 8192);
    };

    f32x4 acc[4][4] = {};
    bf16x8 af[4][2], blo[2][2], bhi[2][2];
    const int swd = (lr & 8) << 2;

    auto loadA = [&](int b) {
#pragma unroll
        for (int mi = 0; mi < 4; ++mi)
#pragma unroll
            for (int ks = 0; ks < 2; ++ks) {
                const int ra = (wr & 1) * 64 + mi * 16 + lr;
                const int off = ((ra >> 4) * 2 + ks) * 1024 + (ra & 15) * 64 + lg * 16;
                af[mi][ks] = *(const bf16x8*)((const char*)As + b * 32768 +
                                              (wr >> 1) * 16384 + (off ^ swd));
            }
    };
    auto loadB = [&](int b, int nh, bf16x8 (&dst)[2][2]) {
#pragma unroll
        for (int nj = 0; nj < 2; ++nj)
#pragma unroll
            for (int ks = 0; ks < 2; ++ks) {
                const int rb = wc * 64 + (nh * 2 + nj) * 16 + lr;
                const int off = ((rb >> 4) * 2 + ks) * 1024 + (rb & 15) * 64 + lg * 16;
                dst[nj][ks] = *(const bf16x8*)((const char*)Bs + b * 16384 +
                                               (off ^ swd));
            }
    };

#define QMM(NH, BF) do {                                                       \
    __builtin_amdgcn_s_setprio(1);                                             \
    _Pragma("unroll")                                                          \
    for (int mi = 0; mi < 4; ++mi) {                                           \
        acc[mi][(NH)*2]   = MFMA16(af[mi][0], (BF)[0][0], acc[mi][(NH)*2]);    \
        acc[mi][(NH)*2]   = MFMA16(af[mi][1], (BF)[0][1], acc[mi][(NH)*2]);    \
        acc[mi][(NH)*2+1] = MFMA16(af[mi][0], (BF)[1][0], acc[mi][(NH)*2+1]);  \
        acc[mi][(NH)*2+1] = MFMA16(af[mi][1], (BF)[1][1], acc[mi][(NH)*2+1]);  \
    }                                                                          \
    __builtin_amdgcn_s_setprio(0);                                             \
} while (0)

    // ---- prologue: stage tile 0, certify ----
    stageA(0, 0, 0); stageA(0, 1, 0); stageB(0, 0);
    VMC(0); BAR();

#pragma unroll 1
    for (int t = 0; t < NT - 1; ++t) {
        const int bc = t & 1, bn = bc ^ 1;
        loadA(bc); loadB(bc, 0, blo);
        stageA(bn, 0, t + 1); stageA(bn, 1, t + 1); stageB(bn, t + 1);
        loadB(bc, 1, bhi);
        QMM(0, blo);
        QMM(1, bhi);
        VMC(0); BAR();
    }
    {
        const int bc = (NT - 1) & 1;
        loadA(bc); loadB(bc, 0, blo);
        loadB(bc, 1, bhi);
        QMM(0, blo);
        QMM(1, bhi);
    }
#undef QMM

#pragma unroll
    for (int mi = 0; mi < 4; ++mi)
#pragma unroll
        for (int ni = 0; ni < 4; ++ni)
#pragma unroll
            for (int j = 0; j < 4; ++j) {
                long r = m0 + wr * 64 + mi * 16 + lg * 4 + j;
                long c = n0 + wc * 64 + ni * 16 + lr;
                C[r * N + c] = (OUT)acc[mi][ni][j];
            }
}

// ---------------------------------------------------------------------------
// RoPE + reshape. In: Cqkv[8192][3072] (q|k|v channel blocks), cos/sin[2048][32].
// Out: Q[bh][s][64], K[bh][s][64] (rope'd), VT[bh][64][2048] (transposed, with
// within-8-column permutation: position p holds key (p&~7)|rotl3(p&7) so the
// attention kernel's PV B-fragment needs NO cross-lane movement).
// ---------------------------------------------------------------------------
__global__ __launch_bounds__(256) void rope_reshape(const bf16_t* __restrict__ Cq,
                                                    const float* __restrict__ fcos,
                                                    const float* __restrict__ fsin,
                                                    bf16_t* __restrict__ Qo,
                                                    bf16_t* __restrict__ Ko,
                                                    bf16_t* __restrict__ VT) {
    __shared__ __attribute__((aligned(16))) bf16_t vt[64][72];
    const int blk = blockIdx.x;
    const int st = blk & 31, bh = blk >> 5;
    const int h = bh & 15, b = bh >> 4;
    const int s0 = st << 6;
    const int tid = threadIdx.x;
    const int i = tid >> 2, dq = (tid & 3) << 4;
    const int s = s0 + i;

    const bf16_t* base = Cq + (long)(b * 2048 + s) * 3072 + h * 64 + dq;
    bf16x8 q0v = *(const bf16x8*)(base);
    bf16x8 q1v = *(const bf16x8*)(base + 8);
    bf16x8 k0v = *(const bf16x8*)(base + 1024);
    bf16x8 k1v = *(const bf16x8*)(base + 1032);
    bf16x8 v0v = *(const bf16x8*)(base + 2048);
    bf16x8 v1v = *(const bf16x8*)(base + 2056);

    float cs[8], sn[8];
    {
        const float* cp = fcos + (long)s * 32 + (dq >> 1);
        const float* sp = fsin + (long)s * 32 + (dq >> 1);
        float4 a = *(const float4*)cp, b2 = *(const float4*)(cp + 4);
        float4 c = *(const float4*)sp, d2 = *(const float4*)(sp + 4);
        cs[0]=a.x; cs[1]=a.y; cs[2]=a.z; cs[3]=a.w; cs[4]=b2.x; cs[5]=b2.y; cs[6]=b2.z; cs[7]=b2.w;
        sn[0]=c.x; sn[1]=c.y; sn[2]=c.z; sn[3]=c.w; sn[4]=d2.x; sn[5]=d2.y; sn[6]=d2.z; sn[7]=d2.w;
    }

    auto rope8 = [&](bf16x8 v, int fo) -> bf16x8 {
        bf16x8 o;
#pragma unroll
        for (int p = 0; p < 4; ++p) {
            float v0 = (float)v[2 * p], v1 = (float)v[2 * p + 1];
            float c = cs[fo + p], s2 = sn[fo + p];
            o[2 * p]     = (bf16_t)(v0 * c - v1 * s2);
            o[2 * p + 1] = (bf16_t)(v0 * s2 + v1 * c);
        }
        return o;
    };

    bf16x8 qo0 = rope8(q0v, 0), qo1 = rope8(q1v, 4);
    bf16x8 ko0 = rope8(k0v, 0), ko1 = rope8(k1v, 4);

    const long qaddr = ((long)bh * 2048 + s) * 64 + dq;
    *(bf16x8*)(Qo + qaddr) = qo0;
    *(bf16x8*)(Qo + qaddr + 8) = qo1;
    *(bf16x8*)(Ko + qaddr) = ko0;
    *(bf16x8*)(Ko + qaddr + 8) = ko1;

    *(bf16x8*)&vt[i][dq] = v0v;
    *(bf16x8*)&vt[i][dq + 8] = v1v;
    __syncthreads();
    const int d = tid >> 2, sb = (tid & 3) << 4;
    bf16x8 o0, o1;
#pragma unroll
    for (int j = 0; j < 8; ++j) {
        const int f = ((j & 3) << 1) | ((j >> 2) & 1);
        o0[j] = vt[sb + f][d];
        o1[j] = vt[sb + 8 + f][d];
    }
    const long va = ((long)bh * 64 + d) * 2048 + s0 + sb;
    *(bf16x8*)(VT + va) = o0;
    *(bf16x8*)(VT + va + 8) = o1;
}

// ---------------------------------------------------------------------------
// Sliding-window attention v4: whole K/V window staged to LDS up front,
// online softmax per 64-key tile, swapped QK^T, P packs directly into the
// PV B-fragment (V^T stored with within-8 key permutation by rope_reshape).
// ---------------------------------------------------------------------------
__global__ __launch_bounds__(256, 2) void attn_win4(const bf16_t* __restrict__ Q,
                                                    const bf16_t* __restrict__ Kb,
                                                    const bf16_t* __restrict__ VT,
                                                    bf16_t* __restrict__ Ao) {
    __shared__ __attribute__((aligned(16))) bf16_t kld[5 * 4096];
    __shared__ __attribute__((aligned(16))) bf16_t vld[5 * 4096];
    const int raw = blockIdx.x;
    const int mswz = ((raw & 7) << 8) | (raw >> 3);
    const int qt = mswz & 31, bh = mswz >> 5;
    const int h = bh & 15, b = bh >> 4;
    const int l = threadIdx.x & 63, w = threadIdx.x >> 6;
    const int lr = l & 15, lg = l >> 4;
    const int q0 = qt * 64 + w * 16;
    const int q = q0 + lr;
    const int tb = qt - 4;

    const bf16_t* Qp = Q + (long)bh * 2048 * 64;
    const bf16_t* Kp = Kb + (long)bh * 2048 * 64;
    const bf16_t* Vp = VT + (long)bh * 64 * 2048;

#pragma unroll
    for (int u = 0; u < 5; ++u) {
        const int kt = tb + u;
        const int kt64 = (kt < 0 ? 0 : kt) * 64;
#pragma unroll
        for (int part = 0; part < 2; ++part) {
            const int seg = w * 2 + part;
            const int r = seg * 8 + (l >> 3);
            const int sc = (l & 7) ^ ((r >> 1) & 7);
            async16(Kp + (long)(kt64 + r) * 64 + sc * 8,
                    (char*)kld + u * 8192 + seg * 1024);
            async16(Vp + (long)r * 2048 + kt64 + sc * 8,
                    (char*)vld + u * 8192 + seg * 1024);
        }
    }

    const bf16x8 qb0 = *(const bf16x8*)&Qp[q * 64 + lg * 8];
    const bf16x8 qb1 = *(const bf16x8*)&Qp[q * 64 + 32 + lg * 8];

    __syncthreads();

    float mrun = -1000.f, lsum = 0.f;
    f32x4 o0 = {0.f, 0.f, 0.f, 0.f}, o1 = {0.f, 0.f, 0.f, 0.f};
    f32x4 o2 = {0.f, 0.f, 0.f, 0.f}, o3 = {0.f, 0.f, 0.f, 0.f};
    const int swv = (lr >> 1) & 7;

#define QKF(DST, HH, MM)                                                         \
    f32x4 DST; {                                                                 \
        const int row_ = (HH) * 32 + 2 * lr + (MM);                              \
        const int sw_ = (row_ >> 1) & 7;                                         \
        bf16x8 k0_ = *(const bf16x8*)(kbase + row_ * 128 + ((lg ^ sw_) << 4));   \
        bf16x8 k1_ = *(const bf16x8*)(kbase + row_ * 128 + (((4 + lg) ^ sw_) << 4)); \
        f32x4 s_ = {0.f, 0.f, 0.f, 0.f};                                         \
        s_ = MFMA16(k0_, qb0, s_);                                               \
        s_ = MFMA16(k1_, qb1, s_);                                               \
        const int kb_ = k0s + (HH) * 32 + (MM) + lg * 8;                         \
        DST[0] = ((kb_ >= 0) & ((unsigned)(q - kb_) < 256u))         ? s_[0] * 0.125f : -1e30f; \
        DST[1] = ((kb_ + 2 >= 0) & ((unsigned)(q - kb_ - 2) < 256u)) ? s_[1] * 0.125f : -1e30f; \
        DST[2] = ((kb_ + 4 >= 0) & ((unsigned)(q - kb_ - 4) < 256u)) ? s_[2] * 0.125f : -1e30f; \
        DST[3] = ((kb_ + 6 >= 0) & ((unsigned)(q - kb_ - 6) < 256u)) ? s_[3] * 0.125f : -1e30f; \
    }

#define EXV(S_) {                                                                \
        S_[0] = __expf(S_[0] - mnew); S_[1] = __expf(S_[1] - mnew);              \
        S_[2] = __expf(S_[2] - mnew); S_[3] = __expf(S_[3] - mnew);              \
        rs += (S_[0] + S_[1]) + (S_[2] + S_[3]); }

#define PVF(NT, HH, PB) {                                                        \
        bf16x8 va_ = *(const bf16x8*)(vbase + ((NT) * 16 + lr) * 128 +           \
                                      ((((HH) * 4 + lg) ^ swv) << 4));           \
        o##NT = MFMA16(va_, PB, o##NT); }

#pragma unroll
    for (int u = 0; u < 5; ++u) {
        const char* kbase = (const char*)kld + u * 8192;
        const char* vbase = (const char*)vld + u * 8192;
        const int k0s = (tb + u) * 64;

        QKF(sA, 0, 0) QKF(sB, 0, 1) QKF(sC, 1, 0) QKF(sD, 1, 1)

        float tm = fmaxf(fmaxf(fmaxf(sA[0], sA[1]), fmaxf(sA[2], sA[3])),
                         fmaxf(fmaxf(sB[0], sB[1]), fmaxf(sB[2], sB[3])));
        tm = fmaxf(tm, fmaxf(fmaxf(fmaxf(sC[0], sC[1]), fmaxf(sC[2], sC[3])),
                             fmaxf(fmaxf(sD[0], sD[1]), fmaxf(sD[2], sD[3]))));
        tm = fmaxf(tm, __shfl_xor(tm, 16));
        tm = fmaxf(tm, __shfl_xor(tm, 32));
        const float mnew = fmaxf(mrun, tm);
        const float alpha = __expf(mrun - mnew);
        mrun = mnew;

        float rs = 0.f;
        EXV(sA) EXV(sB) EXV(sC) EXV(sD)
        rs += __shfl_xor(rs, 16);
        rs += __shfl_xor(rs, 32);
        lsum = lsum * alpha + rs;

        o0[0] *= alpha; o0[1] *= alpha; o0[2] *= alpha; o0[3] *= alpha;
        o1[0] *= alpha; o1[1] *= alpha; o1[2] *= alpha; o1[3] *= alpha;
        o2[0] *= alpha; o2[1] *= alpha; o2[2] *= alpha; o2[3] *= alpha;
        o3[0] *= alpha; o3[1] *= alpha; o3[2] *= alpha; o3[3] *= alpha;

        bf16x8 pb0, pb1;
        pb0[0] = (bf16_t)sA[0]; pb0[1] = (bf16_t)sA[1]; pb0[2] = (bf16_t)sA[2]; pb0[3] = (bf16_t)sA[3];
        pb0[4] = (bf16_t)sB[0]; pb0[5] = (bf16_t)sB[1]; pb0[6] = (bf16_t)sB[2]; pb0[7] = (bf16_t)sB[3];
        pb1[0] = (bf16_t)sC[0]; pb1[1] = (bf16_t)sC[1]; pb1[2] = (bf16_t)sC[2]; pb1[3] = (bf16_t)sC[3];
        pb1[4] = (bf16_t)sD[0]; pb1[5] = (bf16_t)sD[1]; pb1[6] = (bf16_t)sD[2]; pb1[7] = (bf16_t)sD[3];

        PVF(0, 0, pb0) PVF(1, 0, pb0) PVF(2, 0, pb0) PVF(3, 0, pb0)
        PVF(0, 1, pb1) PVF(1, 1, pb1) PVF(2, 1, pb1) PVF(3, 1, pb1)
    }
#undef QKF
#undef EXV
#undef PVF

    const float rinv = 1.0f / lsum;
    bf16_t* aor = Ao + ((long)(b * 2048) + q) * 1024 + h * 64;
#define EPI(NT, OA_) {                                                           \
        bf16x4 ov_;                                                             \
        ov_[0] = (bf16_t)(OA_[0] * rinv); ov_[1] = (bf16_t)(OA_[1] * rinv);      \
        ov_[2] = (bf16_t)(OA_[2] * rinv); ov_[3] = (bf16_t)(OA_[3] * rinv);      \
        *(bf16x4*)(aor + (NT) * 16 + lg * 4) = ov_; }
    EPI(0, o0) EPI(1, o1) EPI(2, o2) EPI(3, o3)
#undef EPI
}

// ---------------------------------------------------------------------------
extern "C" void kernel_launch(void* const* d_in, const int* in_sizes, int n_in,
                              void* d_out, int out_size, void* d_ws, size_t ws_size,
                              hipStream_t stream) {
    (void)in_sizes; (void)n_in; (void)out_size; (void)ws_size;
    const float* x    = (const float*)d_in[0];
    const float* fcos = (const float*)d_in[1];
    const float* fsin = (const float*)d_in[2];
    const float* wq   = (const float*)d_in[3];
    const float* wk   = (const float*)d_in[4];
    const float* wv   = (const float*)d_in[5];
    const float* wo   = (const float*)d_in[6];
    float* out = (float*)d_out;

    char* ws = (char*)d_ws;
    // layout (bytes): xbf 16MB | wqkv 6MB | wobf 2MB | qkvc 48MB | k 16MB | vt 16MB
    bf16_t* xbf  = (bf16_t*)(ws);
    bf16_t* wqkv = (bf16_t*)(ws + 16777216);
    bf16_t* wobf = (bf16_t*)(ws + 23068672);
    bf16_t* qkvc = (bf16_t*)(ws + 25165824);
    bf16_t* kbuf = (bf16_t*)(ws + 75497472);
    bf16_t* vtb  = (bf16_t*)(ws + 92274688);
    bf16_t* qbuf = xbf;   // xbf dead after GEMM1
    bf16_t* aob  = qkvc;  // qkvc dead after rope

    cvt_kernel<<<4096, 256, 0, stream>>>(x, xbf, 8388608);
    cvt_kernel<<<512, 256, 0, stream>>>(wq, wqkv, 1048576);
    cvt_kernel<<<512, 256, 0, stream>>>(wk, wqkv + 1048576, 1048576);
    cvt_kernel<<<512, 256, 0, stream>>>(wv, wqkv + 2097152, 1048576);
    cvt_kernel<<<512, 256, 0, stream>>>(wo, wobf, 1048576);

    // QKV: grid (N/192, M/256) = (16, 32) = 512 blocks = 2 exact rounds
    gemm192<bf16_t><<<dim3(16, 32), 512, 0, stream>>>(xbf, wqkv, qkvc, 8192, 3072, 1024);
    rope_reshape<<<2048, 256, 0, stream>>>(qkvc, fcos, fsin, qbuf, kbuf, vtb);
    attn_win4<<<2048, 256, 0, stream>>>(qbuf, kbuf, vtb, aob);
    // O-proj: grid (8, 32) = 256 blocks = 1 exact round
    gemm256<float><<<dim3(8, 32), 512, 0, stream>>>(aob, wobf, out, 8192, 1024, 1024);
}

// Round 6
// 133.944 us; speedup vs baseline: 1.1471x; 1.1471x over previous
//
#include <hip/hip_runtime.h>
#include <hip/hip_bf16.h>

// ---------------------------------------------------------------------------
// Sliding-window attention (B=4,S=2048,D=1024,H=16,HD=64,W=256) on gfx950.
// Pipeline: cvt(all, fused) -> GEMM(QKV, 256x192 8-phase counted-vmcnt) ->
//           RoPE+reshape (+permuted V^T) -> flash window attention (mask-
//           specialized) -> GEMM(O-proj, 256x128 triple-buffer).
// ---------------------------------------------------------------------------

typedef __bf16 bf16_t;
typedef __attribute__((ext_vector_type(8))) __bf16 bf16x8;
typedef __attribute__((ext_vector_type(4))) __bf16 bf16x4;
typedef __attribute__((ext_vector_type(4))) float f32x4;

#define MFMA16(a, b, c) __builtin_amdgcn_mfma_f32_16x16x32_bf16((a), (b), (c), 0, 0, 0)

// async global->LDS, 16 bytes per lane. LDS dest is wave-uniform base + lane*16.
__device__ __forceinline__ void async16(const void* g, void* l) {
    __builtin_amdgcn_global_load_lds(
        (const __attribute__((address_space(1))) unsigned int*)g,
        (__attribute__((address_space(3))) unsigned int*)l, 16, 0, 0);
}

#define BAR() do { asm volatile("" ::: "memory"); __builtin_amdgcn_s_barrier(); \
                   asm volatile("" ::: "memory"); } while (0)
#define VMC(N) asm volatile("s_waitcnt vmcnt(" #N ")" ::: "memory")

// ---------------------------------------------------------------------------
// Fused f32 -> bf16 convert for all 5 tensors (x + 4 weights), 8 elems/thread.
// Blocks [0,4096): x; [4096,4608): wq; [4608,5120): wk; [5120,5632): wv;
// [5632,6144): wo.  All segments exact multiples of 2048 elems/block.
// ---------------------------------------------------------------------------
__global__ __launch_bounds__(256) void cvt_all(const float* __restrict__ x,
                                               const float* __restrict__ wq,
                                               const float* __restrict__ wk,
                                               const float* __restrict__ wv,
                                               const float* __restrict__ wo,
                                               bf16_t* __restrict__ xbf,
                                               bf16_t* __restrict__ wqkv,
                                               bf16_t* __restrict__ wobf) {
    const int blk = blockIdx.x;
    const float* s;
    bf16_t* d;
    int base;
    if (blk < 4096)      { s = x;  d = xbf;            base = blk; }
    else if (blk < 4608) { s = wq; d = wqkv;           base = blk - 4096; }
    else if (blk < 5120) { s = wk; d = wqkv + 1048576; base = blk - 4608; }
    else if (blk < 5632) { s = wv; d = wqkv + 2097152; base = blk - 5120; }
    else                 { s = wo; d = wobf;           base = blk - 5632; }
    const int i = (base * 256 + threadIdx.x) * 8;
    float4 a = *(const float4*)(s + i);
    float4 b = *(const float4*)(s + i + 4);
    bf16x8 o;
    o[0] = (bf16_t)a.x; o[1] = (bf16_t)a.y; o[2] = (bf16_t)a.z; o[3] = (bf16_t)a.w;
    o[4] = (bf16_t)b.x; o[5] = (bf16_t)b.y; o[6] = (bf16_t)b.z; o[7] = (bf16_t)b.w;
    *(bf16x8*)(d + i) = o;
}

// ---------------------------------------------------------------------------
// 256x192 8-phase GEMM (R4-best): C[M][N] = A[M][K] @ Bw[N][K]^T.
// 512 threads = 8 waves (2M x 4N); per-wave C = 128x48 (acc = 96 regs).
// BK=64.  LDS 112 KiB: A = 2buf x 4units, B = 2buf x 3units; unit = 64x64
// = 8 KiB staged by ONE gload_lds/thread; st_16x32 XOR swizzle, linear LDS
// dest + inverse-swizzled global source + swizzled ds_read.
// 8 phases / 2 K-tiles, 12 MFMA each, counted vmcnt (never 0 in main loop):
//   P4: VMC(1) certifies tile T+1; P8: VMC(3) certifies tile T+2.
// (See R4 notes for FIFO accounting + race-freedom argument.)
// ---------------------------------------------------------------------------
template <typename OUT>
__global__ __launch_bounds__(512, 1) __attribute__((amdgpu_waves_per_eu(2)))
void gemm192(const bf16_t* __restrict__ A, const bf16_t* __restrict__ Bw,
             OUT* __restrict__ C, int M, int N, int K) {
    __shared__ __attribute__((aligned(16))) bf16_t As[32768];   // 2 x 4u x 8KiB
    __shared__ __attribute__((aligned(16))) bf16_t Bs[24576];   // 2 x 3u x 8KiB
    const int tid = threadIdx.x;
    const int l = tid & 63, w = tid >> 6;
    const int lr = l & 15, lg = l >> 4;
    const int wr = w >> 2, wc = w & 3;          // 2M x 4N

    const int nwg = gridDim.x * gridDim.y;
    const int flat = blockIdx.y * gridDim.x + blockIdx.x;
    const int swz = (flat & 7) * (nwg >> 3) + (flat >> 3);
    const int bx = swz % gridDim.x, by = swz / gridDim.x;
    const long m0 = (long)by * 256, n0 = (long)bx * 192;
    const int NT = K >> 6;       // 64-wide K tiles (even, >= 4)
    const int NI = NT >> 1;

    const int p  = w * 1024 + l * 16;
    const int pp = p ^ (((p >> 9) & 1) << 5);
    const int st = pp >> 10;                         // 1 KiB subtile 0..7
    const int rSt = (st >> 1) * 16 + ((pp >> 6) & 15);
    const int cSt = (st & 1) * 32 + ((pp >> 4) & 3) * 8;
    const bf16_t* aS = A  + (m0 + rSt) * K + cSt;
    const bf16_t* bS = Bw + (n0 + rSt) * K + cSt;
    const long uK = 64L * K;                         // unit row stride

    auto stageA = [&](int b, int u, int t) {
        async16(aS + (long)u * uK + (long)t * 64,
                (char*)As + b * 32768 + u * 8192 + w * 1024);
    };
    auto stageB = [&](int b, int u, int t) {
        async16(bS + (long)u * uK + (long)t * 64,
                (char*)Bs + b * 24576 + u * 8192 + w * 1024);
    };

    f32x4 acc[8][3] = {};
    bf16x8 afX[4], afY[4], bfX[3], bfY[3];
    const int swd = (lr & 8) << 2;    // ds_read swizzle: byte bit5 ^= row bit3

    auto loadAF = [&](int b, int mh, int ks, bf16x8 (&dst)[4]) {
#pragma unroll
        for (int mi = 0; mi < 4; ++mi) {
            const int off = (wr * 2 + mh) * 8192 + (mi * 2 + ks) * 1024 +
                            lr * 64 + lg * 16;
            dst[mi] = *(const bf16x8*)((const char*)As + b * 32768 + (off ^ swd));
        }
    };
    auto loadBF = [&](int b, int ks, bf16x8 (&dst)[3]) {
#pragma unroll
        for (int nj = 0; nj < 3; ++nj) {
            const int rg = wc * 48 + nj * 16 + lr;           // N-row 0..191
            const int off = (rg >> 6) * 8192 + (((rg >> 4) & 3) * 2 + ks) * 1024 +
                            lr * 64 + lg * 16;
            dst[nj] = *(const bf16x8*)((const char*)Bs + b * 24576 + (off ^ swd));
        }
    };

#define QMM(MH, AF, BF) do {                                                   \
    __builtin_amdgcn_s_setprio(1);                                             \
    _Pragma("unroll")                                                          \
    for (int mi = 0; mi < 4; ++mi)                                             \
        _Pragma("unroll")                                                      \
        for (int nj = 0; nj < 3; ++nj)                                         \
            acc[(MH)*4+mi][nj] = MFMA16((AF)[mi], (BF)[nj], acc[(MH)*4+mi][nj]); \
    __builtin_amdgcn_s_setprio(0);                                             \
} while (0)

    // ---- prologue: tile0 (A 4u + B 3u), then B(1) 3u; certify tile0 ----
    stageA(0, 0, 0); stageA(0, 1, 0); stageA(0, 2, 0); stageA(0, 3, 0);
    stageB(0, 0, 0); stageB(0, 1, 0); stageB(0, 2, 0);
    stageB(1, 0, 1); stageB(1, 1, 1); stageB(1, 2, 1);
    VMC(3);          // drain tile0's 7, keep B(1)'s 3
    BAR();

#pragma unroll 1
    for (int it = 0; it < NI - 1; ++it) {
        const int T = 2 * it;
        // P1 (tile T, mh0, ks0)
        loadAF(0, 0, 0, afX); loadBF(0, 0, bfX);
        stageA(1, 0, T + 1); stageA(1, 1, T + 1);
        BAR(); QMM(0, afX, bfX); BAR();
        // P2 (mh1, ks0)
        loadAF(0, 1, 0, afY);
        stageA(1, 2, T + 1); stageA(1, 3, T + 1);
        BAR(); QMM(1, afY, bfX); BAR();
        // P3 (mh0, ks1)
        loadAF(0, 0, 1, afX); loadBF(0, 1, bfY);
        BAR(); QMM(0, afX, bfY); BAR();
        // P4 (mh1, ks1): certify tile T+1
        loadAF(0, 1, 1, afY);
        stageB(0, 0, T + 2);
        BAR(); QMM(1, afY, bfY); VMC(1); BAR();
        // P5 (tile T+1, mh0, ks0)
        loadAF(1, 0, 0, afX); loadBF(1, 0, bfX);
        stageB(0, 1, T + 2); stageB(0, 2, T + 2);
        BAR(); QMM(0, afX, bfX); BAR();
        // P6 (mh1, ks0)
        loadAF(1, 1, 0, afY);
        stageA(0, 0, T + 2); stageA(0, 1, T + 2);
        BAR(); QMM(1, afY, bfX); BAR();
        // P7 (mh0, ks1)
        loadAF(1, 0, 1, afX); loadBF(1, 1, bfY);
        stageA(0, 2, T + 2); stageA(0, 3, T + 2);
        BAR(); QMM(0, afX, bfY); BAR();
        // P8 (mh1, ks1): certify tile T+2
        loadAF(1, 1, 1, afY);
        stageB(1, 0, T + 3); stageB(1, 1, T + 3); stageB(1, 2, T + 3);
        BAR(); QMM(1, afY, bfY); VMC(3); BAR();
    }

    // ---- final iteration (tiles NT-2 buf0, NT-1 buf1) ----
    {
        loadAF(0, 0, 0, afX); loadBF(0, 0, bfX);
        stageA(1, 0, NT - 1); stageA(1, 1, NT - 1);
        BAR(); QMM(0, afX, bfX); BAR();
        loadAF(0, 1, 0, afY);
        stageA(1, 2, NT - 1); stageA(1, 3, NT - 1);
        BAR(); QMM(1, afY, bfX); BAR();
        loadAF(0, 0, 1, afX); loadBF(0, 1, bfY);
        BAR(); QMM(0, afX, bfY); BAR();
        loadAF(0, 1, 1, afY);
        BAR(); QMM(1, afY, bfY);
        VMC(0); BAR();   // drain A(NT-1)[4] + B(NT-1)[3]
        // tile NT-1: fully resident, no LDS writers -> no barriers
        loadAF(1, 0, 0, afX); loadBF(1, 0, bfX);
        QMM(0, afX, bfX);
        loadAF(1, 1, 0, afY);
        QMM(1, afY, bfX);
        loadAF(1, 0, 1, afX); loadBF(1, 1, bfY);
        QMM(0, afX, bfY);
        loadAF(1, 1, 1, afY);
        QMM(1, afY, bfY);
    }
#undef QMM

    // ---- epilogue: fragment row = lg*4+j, col = lr ----
#pragma unroll
    for (int ai = 0; ai < 8; ++ai)
#pragma unroll
        for (int nj = 0; nj < 3; ++nj)
#pragma unroll
            for (int j = 0; j < 4; ++j) {
                long r = m0 + wr * 128 + ai * 16 + lg * 4 + j;
                long c = n0 + wc * 48 + nj * 16 + lr;
                C[r * (long)N + c] = (OUT)acc[ai][nj][j];
            }
}

// ---------------------------------------------------------------------------
// 256x128 GEMM (O-proj: N=1024 -> 256 blocks = 1 exact round).
// Triple-buffered deep prefetch, counted vmcnt (R3/R4 version).
// ---------------------------------------------------------------------------
template <typename OUT>
__global__ __launch_bounds__(512, 2) void gemm256(const bf16_t* __restrict__ A,
                                                  const bf16_t* __restrict__ Bw,
                                                  OUT* __restrict__ C,
                                                  int M, int N, int K) {
    __shared__ __attribute__((aligned(16))) bf16_t As[49152];   // 3 x 2 x 128x64
    __shared__ __attribute__((aligned(16))) bf16_t Bs[24576];   // 3 x 128x64
    const int tid = threadIdx.x;
    const int l = tid & 63, w = tid >> 6;
    const int lr = l & 15, lg = l >> 4;
    const int wr = w >> 1, wc = w & 1;

    const int nwg = gridDim.x * gridDim.y;
    const int flat = blockIdx.y * gridDim.x + blockIdx.x;
    const int swz = (flat & 7) * (nwg >> 3) + (flat >> 3);
    const int bx = swz % gridDim.x, by = swz / gridDim.x;
    const long m0 = (long)by * 256, n0 = (long)bx * 128;
    const int NT = K >> 6;

    int rS[2], cS[2];
#pragma unroll
    for (int i = 0; i < 2; ++i) {
        const int p  = i * 8192 + w * 1024 + l * 16;
        const int pp = p ^ (((p >> 9) & 1) << 5);
        const int st = pp >> 10;
        rS[i] = (st >> 1) * 16 + ((pp >> 6) & 15);
        cS[i] = (st & 1) * 32 + ((pp >> 4) & 3) * 8;
    }
    const bf16_t* aSrc0 = A  + (m0 + rS[0]) * K + cS[0];
    const bf16_t* aSrc1 = A  + (m0 + rS[1]) * K + cS[1];
    const bf16_t* bSrc0 = Bw + (n0 + rS[0]) * K + cS[0];
    const bf16_t* bSrc1 = Bw + (n0 + rS[1]) * K + cS[1];
    const long hK = 128L * K;

    auto stageA = [&](int b, int h, int t) {
        char* d = (char*)As + b * 32768 + h * 16384 + w * 1024;
        const long o = (long)h * hK + (long)t * 64;
        async16(aSrc0 + o, d);
        async16(aSrc1 + o, d + 8192);
    };
    auto stageB = [&](int b, int t) {
        char* d = (char*)Bs + b * 16384 + w * 1024;
        const long o = (long)t * 64;
        async16(bSrc0 + o, d);
        async16(bSrc1 + o, d + 8192);
    };

    f32x4 acc[4][4] = {};
    bf16x8 af[4][2], blo[2][2], bhi[2][2];
    const int swd = (lr & 8) << 2;

    auto loadA = [&](int b) {
#pragma unroll
        for (int mi = 0; mi < 4; ++mi)
#pragma unroll
            for (int ks = 0; ks < 2; ++ks) {
                const int ra = (wr & 1) * 64 + mi * 16 + lr;
                const int off = ((ra >> 4) * 2 + ks) * 1024 + (ra & 15) * 64 + lg * 16;
                af[mi][ks] = *(const bf16x8*)((const char*)As + b * 32768 +
                                              (wr >> 1) * 16384 + (off ^ swd));
            }
    };
    auto loadB = [&](int b, int nh, bf16x8 (&dst)[2][2]) {
#pragma unroll
        for (int nj = 0; nj < 2; ++nj)
#pragma unroll
            for (int ks = 0; ks < 2; ++ks) {
                const int rb = wc * 64 + (nh * 2 + nj) * 16 + lr;
                const int off = ((rb >> 4) * 2 + ks) * 1024 + (rb & 15) * 64 + lg * 16;
                dst[nj][ks] = *(const bf16x8*)((const char*)Bs + b * 16384 +
                                               (off ^ swd));
            }
    };

#define QMM(NH, BF) do {                                                       \
    __builtin_amdgcn_s_setprio(1);                                             \
    _Pragma("unroll")                                                          \
    for (int mi = 0; mi < 4; ++mi) {                                           \
        acc[mi][(NH)*2]   = MFMA16(af[mi][0], (BF)[0][0], acc[mi][(NH)*2]);    \
        acc[mi][(NH)*2]   = MFMA16(af[mi][1], (BF)[0][1], acc[mi][(NH)*2]);    \
        acc[mi][(NH)*2+1] = MFMA16(af[mi][0], (BF)[1][0], acc[mi][(NH)*2+1]);  \
        acc[mi][(NH)*2+1] = MFMA16(af[mi][1], (BF)[1][1], acc[mi][(NH)*2+1]);  \
    }                                                                          \
    __builtin_amdgcn_s_setprio(0);                                             \
} while (0)

    stageA(0, 0, 0); stageA(0, 1, 0); stageB(0, 0);
    stageA(1, 0, 1); stageA(1, 1, 1); stageB(1, 1);
    VMC(6);
    BAR();

    int bc = 0;
#pragma unroll 1
    for (int t = 0; t < NT - 2; ++t) {
        const int bn = (bc + 2 >= 3) ? bc - 1 : bc + 2;
        loadA(bc); loadB(bc, 0, blo); stageA(bn, 0, t + 2); stageA(bn, 1, t + 2);
        BAR(); QMM(0, blo); BAR();
        loadB(bc, 1, bhi); stageB(bn, t + 2);
        BAR(); QMM(1, bhi);
        if (t < NT - 3) { VMC(6); } else { VMC(0); }
        BAR();
        bc = (bc + 1 >= 3) ? 0 : bc + 1;
    }
    {
        loadA(bc); loadB(bc, 0, blo);
        QMM(0, blo);
        loadB(bc, 1, bhi);
        QMM(1, bhi);
        const int b2 = (bc + 1 >= 3) ? 0 : bc + 1;
        loadA(b2); loadB(b2, 0, blo);
        QMM(0, blo);
        loadB(b2, 1, bhi);
        QMM(1, bhi);
    }
#undef QMM

#pragma unroll
    for (int mi = 0; mi < 4; ++mi)
#pragma unroll
        for (int ni = 0; ni < 4; ++ni)
#pragma unroll
            for (int j = 0; j < 4; ++j) {
                long r = m0 + wr * 64 + mi * 16 + lg * 4 + j;
                long c = n0 + wc * 64 + ni * 16 + lr;
                C[r * N + c] = (OUT)acc[mi][ni][j];
            }
}

// ---------------------------------------------------------------------------
// RoPE + reshape. In: Cqkv[8192][3072] (q|k|v channel blocks), cos/sin[2048][32].
// Out: Q[bh][s][64], K[bh][s][64] (rope'd), VT[bh][64][2048] (transposed, with
// within-8-column permutation: position p holds key (p&~7)|rotl3(p&7) so the
// attention kernel's PV B-fragment needs NO cross-lane movement).
// ---------------------------------------------------------------------------
__global__ __launch_bounds__(256) void rope_reshape(const bf16_t* __restrict__ Cq,
                                                    const float* __restrict__ fcos,
                                                    const float* __restrict__ fsin,
                                                    bf16_t* __restrict__ Qo,
                                                    bf16_t* __restrict__ Ko,
                                                    bf16_t* __restrict__ VT) {
    __shared__ __attribute__((aligned(16))) bf16_t vt[64][72];
    const int blk = blockIdx.x;
    const int st = blk & 31, bh = blk >> 5;
    const int h = bh & 15, b = bh >> 4;
    const int s0 = st << 6;
    const int tid = threadIdx.x;
    const int i = tid >> 2, dq = (tid & 3) << 4;
    const int s = s0 + i;

    const bf16_t* base = Cq + (long)(b * 2048 + s) * 3072 + h * 64 + dq;
    bf16x8 q0v = *(const bf16x8*)(base);
    bf16x8 q1v = *(const bf16x8*)(base + 8);
    bf16x8 k0v = *(const bf16x8*)(base + 1024);
    bf16x8 k1v = *(const bf16x8*)(base + 1032);
    bf16x8 v0v = *(const bf16x8*)(base + 2048);
    bf16x8 v1v = *(const bf16x8*)(base + 2056);

    float cs[8], sn[8];
    {
        const float* cp = fcos + (long)s * 32 + (dq >> 1);
        const float* sp = fsin + (long)s * 32 + (dq >> 1);
        float4 a = *(const float4*)cp, b2 = *(const float4*)(cp + 4);
        float4 c = *(const float4*)sp, d2 = *(const float4*)(sp + 4);
        cs[0]=a.x; cs[1]=a.y; cs[2]=a.z; cs[3]=a.w; cs[4]=b2.x; cs[5]=b2.y; cs[6]=b2.z; cs[7]=b2.w;
        sn[0]=c.x; sn[1]=c.y; sn[2]=c.z; sn[3]=c.w; sn[4]=d2.x; sn[5]=d2.y; sn[6]=d2.z; sn[7]=d2.w;
    }

    auto rope8 = [&](bf16x8 v, int fo) -> bf16x8 {
        bf16x8 o;
#pragma unroll
        for (int p = 0; p < 4; ++p) {
            float v0 = (float)v[2 * p], v1 = (float)v[2 * p + 1];
            float c = cs[fo + p], s2 = sn[fo + p];
            o[2 * p]     = (bf16_t)(v0 * c - v1 * s2);
            o[2 * p + 1] = (bf16_t)(v0 * s2 + v1 * c);
        }
        return o;
    };

    bf16x8 qo0 = rope8(q0v, 0), qo1 = rope8(q1v, 4);
    bf16x8 ko0 = rope8(k0v, 0), ko1 = rope8(k1v, 4);

    const long qaddr = ((long)bh * 2048 + s) * 64 + dq;
    *(bf16x8*)(Qo + qaddr) = qo0;
    *(bf16x8*)(Qo + qaddr + 8) = qo1;
    *(bf16x8*)(Ko + qaddr) = ko0;
    *(bf16x8*)(Ko + qaddr + 8) = ko1;

    *(bf16x8*)&vt[i][dq] = v0v;
    *(bf16x8*)&vt[i][dq + 8] = v1v;
    __syncthreads();
    const int d = tid >> 2, sb = (tid & 3) << 4;
    bf16x8 o0, o1;
#pragma unroll
    for (int j = 0; j < 8; ++j) {
        const int f = ((j & 3) << 1) | ((j >> 2) & 1);
        o0[j] = vt[sb + f][d];
        o1[j] = vt[sb + 8 + f][d];
    }
    const long va = ((long)bh * 64 + d) * 2048 + s0 + sb;
    *(bf16x8*)(VT + va) = o0;
    *(bf16x8*)(VT + va + 8) = o1;
}

// ---------------------------------------------------------------------------
// Sliding-window attention v5: whole K/V window staged to LDS up front,
// online softmax per 64-key tile, swapped QK^T, P packs directly into the
// PV B-fragment.  MASK SPECIALIZATION (R6): for qt>=4 the per-tile mask is
// statically known: u=0 needs only q-k<256 (q-k in [193,319]); u=1..3 need
// NO mask (q-k in [1,255]); u=4 needs only q-k>=0 (q-k in [-63,63]).
// qt<4 keeps the full mask (handles clamped negative tiles).
// ---------------------------------------------------------------------------
__global__ __launch_bounds__(256, 2) void attn_win4(const bf16_t* __restrict__ Q,
                                                    const bf16_t* __restrict__ Kb,
                                                    const bf16_t* __restrict__ VT,
                                                    bf16_t* __restrict__ Ao) {
    __shared__ __attribute__((aligned(16))) bf16_t kld[5 * 4096];
    __shared__ __attribute__((aligned(16))) bf16_t vld[5 * 4096];
    const int raw = blockIdx.x;
    const int mswz = ((raw & 7) << 8) | (raw >> 3);
    const int qt = mswz & 31, bh = mswz >> 5;
    const int h = bh & 15, b = bh >> 4;
    const int l = threadIdx.x & 63, w = threadIdx.x >> 6;
    const int lr = l & 15, lg = l >> 4;
    const int q0 = qt * 64 + w * 16;
    const int q = q0 + lr;
    const int tb = qt - 4;

    const bf16_t* Qp = Q + (long)bh * 2048 * 64;
    const bf16_t* Kp = Kb + (long)bh * 2048 * 64;
    const bf16_t* Vp = VT + (long)bh * 64 * 2048;

#pragma unroll
    for (int u = 0; u < 5; ++u) {
        const int kt = tb + u;
        const int kt64 = (kt < 0 ? 0 : kt) * 64;
#pragma unroll
        for (int part = 0; part < 2; ++part) {
            const int seg = w * 2 + part;
            const int r = seg * 8 + (l >> 3);
            const int sc = (l & 7) ^ ((r >> 1) & 7);
            async16(Kp + (long)(kt64 + r) * 64 + sc * 8,
                    (char*)kld + u * 8192 + seg * 1024);
            async16(Vp + (long)r * 2048 + kt64 + sc * 8,
                    (char*)vld + u * 8192 + seg * 1024);
        }
    }

    const bf16x8 qb0 = *(const bf16x8*)&Qp[q * 64 + lg * 8];
    const bf16x8 qb1 = *(const bf16x8*)&Qp[q * 64 + 32 + lg * 8];

    __syncthreads();

    float mrun = -1000.f, lsum = 0.f;
    f32x4 o0 = {0.f, 0.f, 0.f, 0.f}, o1 = {0.f, 0.f, 0.f, 0.f};
    f32x4 o2 = {0.f, 0.f, 0.f, 0.f}, o3 = {0.f, 0.f, 0.f, 0.f};
    const int swv = (lr >> 1) & 7;

    const char* kbase;
    const char* vbase;
    int k0s;

// shared QK^T core: 2 MFMA into s_, plus signed distance d_ = q - first key
#define QKCORE(HH, MM)                                                           \
        const int row_ = (HH) * 32 + 2 * lr + (MM);                              \
        const int sw_ = (row_ >> 1) & 7;                                         \
        bf16x8 k0_ = *(const bf16x8*)(kbase + row_ * 128 + ((lg ^ sw_) << 4));   \
        bf16x8 k1_ = *(const bf16x8*)(kbase + row_ * 128 + (((4 + lg) ^ sw_) << 4)); \
        f32x4 s_ = {0.f, 0.f, 0.f, 0.f};                                         \
        s_ = MFMA16(k0_, qb0, s_);                                               \
        s_ = MFMA16(k1_, qb1, s_);

// full mask (qt<4 path; handles clamped tiles): 0 <= q-k < 256 AND k >= 0
#define QKF_F(DST, HH, MM)                                                       \
    f32x4 DST; { QKCORE(HH, MM)                                                  \
        const int kb_ = k0s + (HH) * 32 + (MM) + lg * 8;                         \
        DST[0] = ((kb_ >= 0) & ((unsigned)(q - kb_) < 256u))         ? s_[0] * 0.125f : -1e30f; \
        DST[1] = ((kb_ + 2 >= 0) & ((unsigned)(q - kb_ - 2) < 256u)) ? s_[1] * 0.125f : -1e30f; \
        DST[2] = ((kb_ + 4 >= 0) & ((unsigned)(q - kb_ - 4) < 256u)) ? s_[2] * 0.125f : -1e30f; \
        DST[3] = ((kb_ + 6 >= 0) & ((unsigned)(q - kb_ - 6) < 256u)) ? s_[3] * 0.125f : -1e30f; \
    }

// upper-only mask (u=0, qt>=4): q-k in [193,319] -> only q-k<256 can fail
#define QKF_U(DST, HH, MM)                                                       \
    f32x4 DST; { QKCORE(HH, MM)                                                  \
        const int d_ = q - (k0s + (HH) * 32 + (MM) + lg * 8);                    \
        DST[0] = (d_ < 256)     ? s_[0] * 0.125f : -1e30f;                       \
        DST[1] = (d_ - 2 < 256) ? s_[1] * 0.125f : -1e30f;                       \
        DST[2] = (d_ - 4 < 256) ? s_[2] * 0.125f : -1e30f;                       \
        DST[3] = (d_ - 6 < 256) ? s_[3] * 0.125f : -1e30f;                       \
    }

// lower-only mask (u=4, qt>=4): q-k in [-63,63] -> only q-k>=0 can fail
#define QKF_L(DST, HH, MM)                                                       \
    f32x4 DST; { QKCORE(HH, MM)                                                  \
        const int d_ = q - (k0s + (HH) * 32 + (MM) + lg * 8);                    \
        DST[0] = (d_ >= 0)     ? s_[0] * 0.125f : -1e30f;                        \
        DST[1] = (d_ - 2 >= 0) ? s_[1] * 0.125f : -1e30f;                        \
        DST[2] = (d_ - 4 >= 0) ? s_[2] * 0.125f : -1e30f;                        \
        DST[3] = (d_ - 6 >= 0) ? s_[3] * 0.125f : -1e30f;                        \
    }

// no mask (u=1..3, qt>=4): q-k in [1,255], always valid
#define QKF_N(DST, HH, MM)                                                       \
    f32x4 DST; { QKCORE(HH, MM)                                                  \
        DST[0] = s_[0] * 0.125f; DST[1] = s_[1] * 0.125f;                        \
        DST[2] = s_[2] * 0.125f; DST[3] = s_[3] * 0.125f;                        \
    }

#define EXV(S_) {                                                                \
        S_[0] = __expf(S_[0] - mnew); S_[1] = __expf(S_[1] - mnew);              \
        S_[2] = __expf(S_[2] - mnew); S_[3] = __expf(S_[3] - mnew);              \
        rs += (S_[0] + S_[1]) + (S_[2] + S_[3]); }

#define PVF(NT, HH, PB) {                                                        \
        bf16x8 va_ = *(const bf16x8*)(vbase + ((NT) * 16 + lr) * 128 +           \
                                      ((((HH) * 4 + lg) ^ swv) << 4));           \
        o##NT = MFMA16(va_, PB, o##NT); }

// full per-tile body, parameterized by the QKF variant macro
#define TILEBODY(QKM) {                                                          \
        QKM(sA, 0, 0) QKM(sB, 0, 1) QKM(sC, 1, 0) QKM(sD, 1, 1)                  \
        float tm = fmaxf(fmaxf(fmaxf(sA[0], sA[1]), fmaxf(sA[2], sA[3])),        \
                         fmaxf(fmaxf(sB[0], sB[1]), fmaxf(sB[2], sB[3])));       \
        tm = fmaxf(tm, fmaxf(fmaxf(fmaxf(sC[0], sC[1]), fmaxf(sC[2], sC[3])),    \
                             fmaxf(fmaxf(sD[0], sD[1]), fmaxf(sD[2], sD[3]))));  \
        tm = fmaxf(tm, __shfl_xor(tm, 16));                                      \
        tm = fmaxf(tm, __shfl_xor(tm, 32));                                      \
        const float mnew = fmaxf(mrun, tm);                                      \
        const float alpha = __expf(mrun - mnew);                                 \
        mrun = mnew;                                                             \
        float rs = 0.f;                                                          \
        EXV(sA) EXV(sB) EXV(sC) EXV(sD)                                          \
        rs += __shfl_xor(rs, 16);                                                \
        rs += __shfl_xor(rs, 32);                                                \
        lsum = lsum * alpha + rs;                                                \
        o0[0] *= alpha; o0[1] *= alpha; o0[2] *= alpha; o0[3] *= alpha;          \
        o1[0] *= alpha; o1[1] *= alpha; o1[2] *= alpha; o1[3] *= alpha;          \
        o2[0] *= alpha; o2[1] *= alpha; o2[2] *= alpha; o2[3] *= alpha;          \
        o3[0] *= alpha; o3[1] *= alpha; o3[2] *= alpha; o3[3] *= alpha;          \
        bf16x8 pb0, pb1;                                                         \
        pb0[0] = (bf16_t)sA[0]; pb0[1] = (bf16_t)sA[1]; pb0[2] = (bf16_t)sA[2]; pb0[3] = (bf16_t)sA[3]; \
        pb0[4] = (bf16_t)sB[0]; pb0[5] = (bf16_t)sB[1]; pb0[6] = (bf16_t)sB[2]; pb0[7] = (bf16_t)sB[3]; \
        pb1[0] = (bf16_t)sC[0]; pb1[1] = (bf16_t)sC[1]; pb1[2] = (bf16_t)sC[2]; pb1[3] = (bf16_t)sC[3]; \
        pb1[4] = (bf16_t)sD[0]; pb1[5] = (bf16_t)sD[1]; pb1[6] = (bf16_t)sD[2]; pb1[7] = (bf16_t)sD[3]; \
        PVF(0, 0, pb0) PVF(1, 0, pb0) PVF(2, 0, pb0) PVF(3, 0, pb0)              \
        PVF(0, 1, pb1) PVF(1, 1, pb1) PVF(2, 1, pb1) PVF(3, 1, pb1)              \
    }

#define SETT(U) kbase = (const char*)kld + (U) * 8192;                           \
                vbase = (const char*)vld + (U) * 8192;                           \
                k0s = (tb + (U)) * 64;

    if (qt >= 4) {
        SETT(0) TILEBODY(QKF_U)
        SETT(1) TILEBODY(QKF_N)
        SETT(2) TILEBODY(QKF_N)
        SETT(3) TILEBODY(QKF_N)
        SETT(4) TILEBODY(QKF_L)
    } else {
#pragma unroll
        for (int u = 0; u < 5; ++u) {
            SETT(u) TILEBODY(QKF_F)
        }
    }
#undef SETT
#undef TILEBODY
#undef QKF_F
#undef QKF_U
#undef QKF_L
#undef QKF_N
#undef QKCORE
#undef EXV
#undef PVF

    const float rinv = 1.0f / lsum;
    bf16_t* aor = Ao + ((long)(b * 2048) + q) * 1024 + h * 64;
#define EPI(NT, OA_) {                                                           \
        bf16x4 ov_;                                                             \
        ov_[0] = (bf16_t)(OA_[0] * rinv); ov_[1] = (bf16_t)(OA_[1] * rinv);      \
        ov_[2] = (bf16_t)(OA_[2] * rinv); ov_[3] = (bf16_t)(OA_[3] * rinv);      \
        *(bf16x4*)(aor + (NT) * 16 + lg * 4) = ov_; }
    EPI(0, o0) EPI(1, o1) EPI(2, o2) EPI(3, o3)
#undef EPI
}

// ---------------------------------------------------------------------------
extern "C" void kernel_launch(void* const* d_in, const int* in_sizes, int n_in,
                              void* d_out, int out_size, void* d_ws, size_t ws_size,
                              hipStream_t stream) {
    (void)in_sizes; (void)n_in; (void)out_size; (void)ws_size;
    const float* x    = (const float*)d_in[0];
    const float* fcos = (const float*)d_in[1];
    const float* fsin = (const float*)d_in[2];
    const float* wq   = (const float*)d_in[3];
    const float* wk   = (const float*)d_in[4];
    const float* wv   = (const float*)d_in[5];
    const float* wo   = (const float*)d_in[6];
    float* out = (float*)d_out;

    char* ws = (char*)d_ws;
    // layout (bytes): xbf 16MB | wqkv 6MB | wobf 2MB | qkvc 48MB | k 16MB | vt 16MB
    bf16_t* xbf  = (bf16_t*)(ws);
    bf16_t* wqkv = (bf16_t*)(ws + 16777216);
    bf16_t* wobf = (bf16_t*)(ws + 23068672);
    bf16_t* qkvc = (bf16_t*)(ws + 25165824);
    bf16_t* kbuf = (bf16_t*)(ws + 75497472);
    bf16_t* vtb  = (bf16_t*)(ws + 92274688);
    bf16_t* qbuf = xbf;   // xbf dead after GEMM1
    bf16_t* aob  = qkvc;  // qkvc dead after rope

    cvt_all<<<6144, 256, 0, stream>>>(x, wq, wk, wv, wo, xbf, wqkv, wobf);

    // QKV: grid (N/192, M/256) = (16, 32) = 512 blocks = 2 exact rounds
    gemm192<bf16_t><<<dim3(16, 32), 512, 0, stream>>>(xbf, wqkv, qkvc, 8192, 3072, 1024);
    rope_reshape<<<2048, 256, 0, stream>>>(qkvc, fcos, fsin, qbuf, kbuf, vtb);
    attn_win4<<<2048, 256, 0, stream>>>(qbuf, kbuf, vtb, aob);
    // O-proj: grid (8, 32) = 256 blocks = 1 exact round
    gemm256<float><<<dim3(8, 32), 512, 0, stream>>>(aob, wobf, out, 8192, 1024, 1024);
}

// Round 7
// 130.097 us; speedup vs baseline: 1.1810x; 1.0296x over previous
//
#include <hip/hip_runtime.h>
#include <hip/hip_bf16.h>

// ---------------------------------------------------------------------------
// Sliding-window attention (B=4,S=2048,D=1024,H=16,HD=64,W=256) on gfx950.
// Pipeline: cvt(all, fused) -> GEMM(QKV, 256x192 8-phase, FUSED RoPE+layout
//           epilogue: writes Q/K in [bh][s][64] + V passthrough) ->
//           vt_transpose (V -> VT with within-8 perm) -> flash window
//           attention (mask-specialized) -> GEMM(O-proj, 256x128 3-buffer).
// ---------------------------------------------------------------------------

typedef __bf16 bf16_t;
typedef __attribute__((ext_vector_type(8))) __bf16 bf16x8;
typedef __attribute__((ext_vector_type(4))) __bf16 bf16x4;
typedef __attribute__((ext_vector_type(4))) float f32x4;

#define MFMA16(a, b, c) __builtin_amdgcn_mfma_f32_16x16x32_bf16((a), (b), (c), 0, 0, 0)

// async global->LDS, 16 bytes per lane. LDS dest is wave-uniform base + lane*16.
__device__ __forceinline__ void async16(const void* g, void* l) {
    __builtin_amdgcn_global_load_lds(
        (const __attribute__((address_space(1))) unsigned int*)g,
        (__attribute__((address_space(3))) unsigned int*)l, 16, 0, 0);
}

#define BAR() do { asm volatile("" ::: "memory"); __builtin_amdgcn_s_barrier(); \
                   asm volatile("" ::: "memory"); } while (0)
#define VMC(N) asm volatile("s_waitcnt vmcnt(" #N ")" ::: "memory")

// ---------------------------------------------------------------------------
// Fused f32 -> bf16 convert for all 5 tensors (x + 4 weights), 8 elems/thread.
// ---------------------------------------------------------------------------
__global__ __launch_bounds__(256) void cvt_all(const float* __restrict__ x,
                                               const float* __restrict__ wq,
                                               const float* __restrict__ wk,
                                               const float* __restrict__ wv,
                                               const float* __restrict__ wo,
                                               bf16_t* __restrict__ xbf,
                                               bf16_t* __restrict__ wqkv,
                                               bf16_t* __restrict__ wobf) {
    const int blk = blockIdx.x;
    const float* s;
    bf16_t* d;
    int base;
    if (blk < 4096)      { s = x;  d = xbf;            base = blk; }
    else if (blk < 4608) { s = wq; d = wqkv;           base = blk - 4096; }
    else if (blk < 5120) { s = wk; d = wqkv + 1048576; base = blk - 4608; }
    else if (blk < 5632) { s = wv; d = wqkv + 2097152; base = blk - 5120; }
    else                 { s = wo; d = wobf;           base = blk - 5632; }
    const int i = (base * 256 + threadIdx.x) * 8;
    float4 a = *(const float4*)(s + i);
    float4 b = *(const float4*)(s + i + 4);
    bf16x8 o;
    o[0] = (bf16_t)a.x; o[1] = (bf16_t)a.y; o[2] = (bf16_t)a.z; o[3] = (bf16_t)a.w;
    o[4] = (bf16_t)b.x; o[5] = (bf16_t)b.y; o[6] = (bf16_t)b.z; o[7] = (bf16_t)b.w;
    *(bf16x8*)(d + i) = o;
}

// ---------------------------------------------------------------------------
// 256x192 8-phase QKV GEMM with FUSED RoPE epilogue.
// Main loop identical to R4/R6 (counted vmcnt, st_16x32 swizzle, 8 waves).
// Epilogue: each fragment (16 cols) is entirely q, k, or v class (boundaries
// 1024/2048 are multiples of 16; class = cbase>>10, wave-uniform).
//   q/k: RoPE in-register: partner value via __shfl_xor(v,1) (adjacent lanes
//        hold adjacent channels of the same token); o = v*cos + sgn*pv*sin,
//        sgn = lane parity; store to Q/K [bh][s][64] (16-lane x 2B rows,
//        same coalescing as the old C-write).
//   v:   passthrough to vtmp[token][1024] (transposed later).
// ---------------------------------------------------------------------------
__global__ __launch_bounds__(512, 1) __attribute__((amdgpu_waves_per_eu(2)))
void gemm192_qkv(const bf16_t* __restrict__ A, const bf16_t* __restrict__ Bw,
                 const float* __restrict__ fcos, const float* __restrict__ fsin,
                 bf16_t* __restrict__ Qo, bf16_t* __restrict__ Ko,
                 bf16_t* __restrict__ Vtmp, int M, int N, int K) {
    __shared__ __attribute__((aligned(16))) bf16_t As[32768];   // 2 x 4u x 8KiB
    __shared__ __attribute__((aligned(16))) bf16_t Bs[24576];   // 2 x 3u x 8KiB
    const int tid = threadIdx.x;
    const int l = tid & 63, w = tid >> 6;
    const int lr = l & 15, lg = l >> 4;
    const int wr = w >> 2, wc = w & 3;          // 2M x 4N

    const int nwg = gridDim.x * gridDim.y;
    const int flat = blockIdx.y * gridDim.x + blockIdx.x;
    const int swz = (flat & 7) * (nwg >> 3) + (flat >> 3);
    const int bx = swz % gridDim.x, by = swz / gridDim.x;
    const long m0 = (long)by * 256, n0 = (long)bx * 192;
    const int NT = K >> 6;
    const int NI = NT >> 1;

    const int p  = w * 1024 + l * 16;
    const int pp = p ^ (((p >> 9) & 1) << 5);
    const int st = pp >> 10;
    const int rSt = (st >> 1) * 16 + ((pp >> 6) & 15);
    const int cSt = (st & 1) * 32 + ((pp >> 4) & 3) * 8;
    const bf16_t* aS = A  + (m0 + rSt) * K + cSt;
    const bf16_t* bS = Bw + (n0 + rSt) * K + cSt;
    const long uK = 64L * K;

    auto stageA = [&](int b, int u, int t) {
        async16(aS + (long)u * uK + (long)t * 64,
                (char*)As + b * 32768 + u * 8192 + w * 1024);
    };
    auto stageB = [&](int b, int u, int t) {
        async16(bS + (long)u * uK + (long)t * 64,
                (char*)Bs + b * 24576 + u * 8192 + w * 1024);
    };

    f32x4 acc[8][3] = {};
    bf16x8 afX[4], afY[4], bfX[3], bfY[3];
    const int swd = (lr & 8) << 2;

    auto loadAF = [&](int b, int mh, int ks, bf16x8 (&dst)[4]) {
#pragma unroll
        for (int mi = 0; mi < 4; ++mi) {
            const int off = (wr * 2 + mh) * 8192 + (mi * 2 + ks) * 1024 +
                            lr * 64 + lg * 16;
            dst[mi] = *(const bf16x8*)((const char*)As + b * 32768 + (off ^ swd));
        }
    };
    auto loadBF = [&](int b, int ks, bf16x8 (&dst)[3]) {
#pragma unroll
        for (int nj = 0; nj < 3; ++nj) {
            const int rg = wc * 48 + nj * 16 + lr;
            const int off = (rg >> 6) * 8192 + (((rg >> 4) & 3) * 2 + ks) * 1024 +
                            lr * 64 + lg * 16;
            dst[nj] = *(const bf16x8*)((const char*)Bs + b * 24576 + (off ^ swd));
        }
    };

#define QMM(MH, AF, BF) do {                                                   \
    __builtin_amdgcn_s_setprio(1);                                             \
    _Pragma("unroll")                                                          \
    for (int mi = 0; mi < 4; ++mi)                                             \
        _Pragma("unroll")                                                      \
        for (int nj = 0; nj < 3; ++nj)                                         \
            acc[(MH)*4+mi][nj] = MFMA16((AF)[mi], (BF)[nj], acc[(MH)*4+mi][nj]); \
    __builtin_amdgcn_s_setprio(0);                                             \
} while (0)

    // ---- prologue ----
    stageA(0, 0, 0); stageA(0, 1, 0); stageA(0, 2, 0); stageA(0, 3, 0);
    stageB(0, 0, 0); stageB(0, 1, 0); stageB(0, 2, 0);
    stageB(1, 0, 1); stageB(1, 1, 1); stageB(1, 2, 1);
    VMC(3);
    BAR();

#pragma unroll 1
    for (int it = 0; it < NI - 1; ++it) {
        const int T = 2 * it;
        loadAF(0, 0, 0, afX); loadBF(0, 0, bfX);
        stageA(1, 0, T + 1); stageA(1, 1, T + 1);
        BAR(); QMM(0, afX, bfX); BAR();
        loadAF(0, 1, 0, afY);
        stageA(1, 2, T + 1); stageA(1, 3, T + 1);
        BAR(); QMM(1, afY, bfX); BAR();
        loadAF(0, 0, 1, afX); loadBF(0, 1, bfY);
        BAR(); QMM(0, afX, bfY); BAR();
        loadAF(0, 1, 1, afY);
        stageB(0, 0, T + 2);
        BAR(); QMM(1, afY, bfY); VMC(1); BAR();
        loadAF(1, 0, 0, afX); loadBF(1, 0, bfX);
        stageB(0, 1, T + 2); stageB(0, 2, T + 2);
        BAR(); QMM(0, afX, bfX); BAR();
        loadAF(1, 1, 0, afY);
        stageA(0, 0, T + 2); stageA(0, 1, T + 2);
        BAR(); QMM(1, afY, bfX); BAR();
        loadAF(1, 0, 1, afX); loadBF(1, 1, bfY);
        stageA(0, 2, T + 2); stageA(0, 3, T + 2);
        BAR(); QMM(0, afX, bfY); BAR();
        loadAF(1, 1, 1, afY);
        stageB(1, 0, T + 3); stageB(1, 1, T + 3); stageB(1, 2, T + 3);
        BAR(); QMM(1, afY, bfY); VMC(3); BAR();
    }

    // ---- final iteration ----
    {
        loadAF(0, 0, 0, afX); loadBF(0, 0, bfX);
        stageA(1, 0, NT - 1); stageA(1, 1, NT - 1);
        BAR(); QMM(0, afX, bfX); BAR();
        loadAF(0, 1, 0, afY);
        stageA(1, 2, NT - 1); stageA(1, 3, NT - 1);
        BAR(); QMM(1, afY, bfX); BAR();
        loadAF(0, 0, 1, afX); loadBF(0, 1, bfY);
        BAR(); QMM(0, afX, bfY); BAR();
        loadAF(0, 1, 1, afY);
        BAR(); QMM(1, afY, bfY);
        VMC(0); BAR();
        loadAF(1, 0, 0, afX); loadBF(1, 0, bfX);
        QMM(0, afX, bfX);
        loadAF(1, 1, 0, afY);
        QMM(1, afY, bfX);
        loadAF(1, 0, 1, afX); loadBF(1, 1, bfY);
        QMM(0, afX, bfY);
        loadAF(1, 1, 1, afY);
        QMM(1, afY, bfY);
    }
#undef QMM

    // ---- FUSED epilogue: RoPE(Q,K) + V passthrough ----
#pragma unroll
    for (int nj = 0; nj < 3; ++nj) {
        const int cbase = (int)n0 + wc * 48 + nj * 16;   // multiple of 16
        const int cls = cbase >> 10;                     // 0=q,1=k,2=v (wave-uniform)
        const int c = cbase + lr;
        if (cls == 2) {
            bf16_t* vp = Vtmp + (c - 2048);
#pragma unroll
            for (int ai = 0; ai < 8; ++ai)
#pragma unroll
                for (int j = 0; j < 4; ++j) {
                    const long t = m0 + wr * 128 + ai * 16 + lg * 4 + j;
                    vp[t * 1024] = (bf16_t)acc[ai][nj][j];
                }
        } else {
            const int d = c & 63;
            const int p2 = d >> 1;                       // freq index (pair)
            const int h = (c >> 6) & 15;
            const float sgn = (lr & 1) ? 1.f : -1.f;
            bf16_t* qk = (cls == 0) ? Qo : Ko;
#pragma unroll
            for (int ai = 0; ai < 8; ++ai)
#pragma unroll
                for (int j = 0; j < 4; ++j) {
                    const long t = m0 + wr * 128 + ai * 16 + lg * 4 + j;
                    const int s = (int)(t & 2047);
                    const int bb = (int)(t >> 11);
                    const float v = acc[ai][nj][j];
                    const float pv = __shfl_xor(v, 1);   // partner channel, same token
                    const float cc = fcos[s * 32 + p2];
                    const float ss = fsin[s * 32 + p2];
                    const float o = v * cc + sgn * (pv * ss);
                    qk[((long)(bb * 16 + h) * 2048 + s) * 64 + d] = (bf16_t)o;
                }
        }
    }
}

// ---------------------------------------------------------------------------
// V -> VT transpose (+ within-8 key permutation: position p holds key
// (p&~7)|rotl3(p&7)).  In: V[8192][1024] (token-major). Out: VT[bh][64][2048].
// Same LDS path as the old rope_reshape V branch; 32 MB total traffic.
// ---------------------------------------------------------------------------
__global__ __launch_bounds__(256) void vt_transpose(const bf16_t* __restrict__ V,
                                                    bf16_t* __restrict__ VT) {
    __shared__ __attribute__((aligned(16))) bf16_t vt[64][72];
    const int blk = blockIdx.x;
    const int st = blk & 31, bh = blk >> 5;
    const int h = bh & 15, b = bh >> 4;
    const int s0 = st << 6;
    const int tid = threadIdx.x;
    const int i = tid >> 2, dq = (tid & 3) << 4;
    const int s = s0 + i;

    const bf16_t* base = V + (long)(b * 2048 + s) * 1024 + h * 64 + dq;
    bf16x8 v0v = *(const bf16x8*)(base);
    bf16x8 v1v = *(const bf16x8*)(base + 8);

    *(bf16x8*)&vt[i][dq] = v0v;
    *(bf16x8*)&vt[i][dq + 8] = v1v;
    __syncthreads();
    const int d = tid >> 2, sb = (tid & 3) << 4;
    bf16x8 o0, o1;
#pragma unroll
    for (int j = 0; j < 8; ++j) {
        const int f = ((j & 3) << 1) | ((j >> 2) & 1);   // position j holds key f
        o0[j] = vt[sb + f][d];
        o1[j] = vt[sb + 8 + f][d];
    }
    const long va = ((long)bh * 64 + d) * 2048 + s0 + sb;
    *(bf16x8*)(VT + va) = o0;
    *(bf16x8*)(VT + va + 8) = o1;
}

// ---------------------------------------------------------------------------
// 256x128 GEMM (O-proj: N=1024 -> 256 blocks = 1 exact round).
// Triple-buffered deep prefetch, counted vmcnt (R3/R4 version).
// ---------------------------------------------------------------------------
template <typename OUT>
__global__ __launch_bounds__(512, 2) void gemm256(const bf16_t* __restrict__ A,
                                                  const bf16_t* __restrict__ Bw,
                                                  OUT* __restrict__ C,
                                                  int M, int N, int K) {
    __shared__ __attribute__((aligned(16))) bf16_t As[49152];   // 3 x 2 x 128x64
    __shared__ __attribute__((aligned(16))) bf16_t Bs[24576];   // 3 x 128x64
    const int tid = threadIdx.x;
    const int l = tid & 63, w = tid >> 6;
    const int lr = l & 15, lg = l >> 4;
    const int wr = w >> 1, wc = w & 1;

    const int nwg = gridDim.x * gridDim.y;
    const int flat = blockIdx.y * gridDim.x + blockIdx.x;
    const int swz = (flat & 7) * (nwg >> 3) + (flat >> 3);
    const int bx = swz % gridDim.x, by = swz / gridDim.x;
    const long m0 = (long)by * 256, n0 = (long)bx * 128;
    const int NT = K >> 6;

    int rS[2], cS[2];
#pragma unroll
    for (int i = 0; i < 2; ++i) {
        const int p  = i * 8192 + w * 1024 + l * 16;
        const int pp = p ^ (((p >> 9) & 1) << 5);
        const int st = pp >> 10;
        rS[i] = (st >> 1) * 16 + ((pp >> 6) & 15);
        cS[i] = (st & 1) * 32 + ((pp >> 4) & 3) * 8;
    }
    const bf16_t* aSrc0 = A  + (m0 + rS[0]) * K + cS[0];
    const bf16_t* aSrc1 = A  + (m0 + rS[1]) * K + cS[1];
    const bf16_t* bSrc0 = Bw + (n0 + rS[0]) * K + cS[0];
    const bf16_t* bSrc1 = Bw + (n0 + rS[1]) * K + cS[1];
    const long hK = 128L * K;

    auto stageA = [&](int b, int h, int t) {
        char* d = (char*)As + b * 32768 + h * 16384 + w * 1024;
        const long o = (long)h * hK + (long)t * 64;
        async16(aSrc0 + o, d);
        async16(aSrc1 + o, d + 8192);
    };
    auto stageB = [&](int b, int t) {
        char* d = (char*)Bs + b * 16384 + w * 1024;
        const long o = (long)t * 64;
        async16(bSrc0 + o, d);
        async16(bSrc1 + o, d + 8192);
    };

    f32x4 acc[4][4] = {};
    bf16x8 af[4][2], blo[2][2], bhi[2][2];
    const int swd = (lr & 8) << 2;

    auto loadA = [&](int b) {
#pragma unroll
        for (int mi = 0; mi < 4; ++mi)
#pragma unroll
            for (int ks = 0; ks < 2; ++ks) {
                const int ra = (wr & 1) * 64 + mi * 16 + lr;
                const int off = ((ra >> 4) * 2 + ks) * 1024 + (ra & 15) * 64 + lg * 16;
                af[mi][ks] = *(const bf16x8*)((const char*)As + b * 32768 +
                                              (wr >> 1) * 16384 + (off ^ swd));
            }
    };
    auto loadB = [&](int b, int nh, bf16x8 (&dst)[2][2]) {
#pragma unroll
        for (int nj = 0; nj < 2; ++nj)
#pragma unroll
            for (int ks = 0; ks < 2; ++ks) {
                const int rb = wc * 64 + (nh * 2 + nj) * 16 + lr;
                const int off = ((rb >> 4) * 2 + ks) * 1024 + (rb & 15) * 64 + lg * 16;
                dst[nj][ks] = *(const bf16x8*)((const char*)Bs + b * 16384 +
                                               (off ^ swd));
            }
    };

#define QMM(NH, BF) do {                                                       \
    __builtin_amdgcn_s_setprio(1);                                             \
    _Pragma("unroll")                                                          \
    for (int mi = 0; mi < 4; ++mi) {                                           \
        acc[mi][(NH)*2]   = MFMA16(af[mi][0], (BF)[0][0], acc[mi][(NH)*2]);    \
        acc[mi][(NH)*2]   = MFMA16(af[mi][1], (BF)[0][1], acc[mi][(NH)*2]);    \
        acc[mi][(NH)*2+1] = MFMA16(af[mi][0], (BF)[1][0], acc[mi][(NH)*2+1]);  \
        acc[mi][(NH)*2+1] = MFMA16(af[mi][1], (BF)[1][1], acc[mi][(NH)*2+1]);  \
    }                                                                          \
    __builtin_amdgcn_s_setprio(0);                                             \
} while (0)

    stageA(0, 0, 0); stageA(0, 1, 0); stageB(0, 0);
    stageA(1, 0, 1); stageA(1, 1, 1); stageB(1, 1);
    VMC(6);
    BAR();

    int bc = 0;
#pragma unroll 1
    for (int t = 0; t < NT - 2; ++t) {
        const int bn = (bc + 2 >= 3) ? bc - 1 : bc + 2;
        loadA(bc); loadB(bc, 0, blo); stageA(bn, 0, t + 2); stageA(bn, 1, t + 2);
        BAR(); QMM(0, blo); BAR();
        loadB(bc, 1, bhi); stageB(bn, t + 2);
        BAR(); QMM(1, bhi);
        if (t < NT - 3) { VMC(6); } else { VMC(0); }
        BAR();
        bc = (bc + 1 >= 3) ? 0 : bc + 1;
    }
    {
        loadA(bc); loadB(bc, 0, blo);
        QMM(0, blo);
        loadB(bc, 1, bhi);
        QMM(1, bhi);
        const int b2 = (bc + 1 >= 3) ? 0 : bc + 1;
        loadA(b2); loadB(b2, 0, blo);
        QMM(0, blo);
        loadB(b2, 1, bhi);
        QMM(1, bhi);
    }
#undef QMM

#pragma unroll
    for (int mi = 0; mi < 4; ++mi)
#pragma unroll
        for (int ni = 0; ni < 4; ++ni)
#pragma unroll
            for (int j = 0; j < 4; ++j) {
                long r = m0 + wr * 64 + mi * 16 + lg * 4 + j;
                long c = n0 + wc * 64 + ni * 16 + lr;
                C[r * N + c] = (OUT)acc[mi][ni][j];
            }
}

// ---------------------------------------------------------------------------
// Sliding-window attention v5 (R6): whole K/V window staged to LDS up front,
// online softmax per 64-key tile, swapped QK^T, mask specialization for
// qt>=4 (u=0 upper-only, u=1..3 no mask, u=4 lower-only).
// ---------------------------------------------------------------------------
__global__ __launch_bounds__(256, 2) void attn_win4(const bf16_t* __restrict__ Q,
                                                    const bf16_t* __restrict__ Kb,
                                                    const bf16_t* __restrict__ VT,
                                                    bf16_t* __restrict__ Ao) {
    __shared__ __attribute__((aligned(16))) bf16_t kld[5 * 4096];
    __shared__ __attribute__((aligned(16))) bf16_t vld[5 * 4096];
    const int raw = blockIdx.x;
    const int mswz = ((raw & 7) << 8) | (raw >> 3);
    const int qt = mswz & 31, bh = mswz >> 5;
    const int h = bh & 15, b = bh >> 4;
    const int l = threadIdx.x & 63, w = threadIdx.x >> 6;
    const int lr = l & 15, lg = l >> 4;
    const int q0 = qt * 64 + w * 16;
    const int q = q0 + lr;
    const int tb = qt - 4;

    const bf16_t* Qp = Q + (long)bh * 2048 * 64;
    const bf16_t* Kp = Kb + (long)bh * 2048 * 64;
    const bf16_t* Vp = VT + (long)bh * 64 * 2048;

#pragma unroll
    for (int u = 0; u < 5; ++u) {
        const int kt = tb + u;
        const int kt64 = (kt < 0 ? 0 : kt) * 64;
#pragma unroll
        for (int part = 0; part < 2; ++part) {
            const int seg = w * 2 + part;
            const int r = seg * 8 + (l >> 3);
            const int sc = (l & 7) ^ ((r >> 1) & 7);
            async16(Kp + (long)(kt64 + r) * 64 + sc * 8,
                    (char*)kld + u * 8192 + seg * 1024);
            async16(Vp + (long)r * 2048 + kt64 + sc * 8,
                    (char*)vld + u * 8192 + seg * 1024);
        }
    }

    const bf16x8 qb0 = *(const bf16x8*)&Qp[q * 64 + lg * 8];
    const bf16x8 qb1 = *(const bf16x8*)&Qp[q * 64 + 32 + lg * 8];

    __syncthreads();

    float mrun = -1000.f, lsum = 0.f;
    f32x4 o0 = {0.f, 0.f, 0.f, 0.f}, o1 = {0.f, 0.f, 0.f, 0.f};
    f32x4 o2 = {0.f, 0.f, 0.f, 0.f}, o3 = {0.f, 0.f, 0.f, 0.f};
    const int swv = (lr >> 1) & 7;

    const char* kbase;
    const char* vbase;
    int k0s;

#define QKCORE(HH, MM)                                                           \
        const int row_ = (HH) * 32 + 2 * lr + (MM);                              \
        const int sw_ = (row_ >> 1) & 7;                                         \
        bf16x8 k0_ = *(const bf16x8*)(kbase + row_ * 128 + ((lg ^ sw_) << 4));   \
        bf16x8 k1_ = *(const bf16x8*)(kbase + row_ * 128 + (((4 + lg) ^ sw_) << 4)); \
        f32x4 s_ = {0.f, 0.f, 0.f, 0.f};                                         \
        s_ = MFMA16(k0_, qb0, s_);                                               \
        s_ = MFMA16(k1_, qb1, s_);

#define QKF_F(DST, HH, MM)                                                       \
    f32x4 DST; { QKCORE(HH, MM)                                                  \
        const int kb_ = k0s + (HH) * 32 + (MM) + lg * 8;                         \
        DST[0] = ((kb_ >= 0) & ((unsigned)(q - kb_) < 256u))         ? s_[0] * 0.125f : -1e30f; \
        DST[1] = ((kb_ + 2 >= 0) & ((unsigned)(q - kb_ - 2) < 256u)) ? s_[1] * 0.125f : -1e30f; \
        DST[2] = ((kb_ + 4 >= 0) & ((unsigned)(q - kb_ - 4) < 256u)) ? s_[2] * 0.125f : -1e30f; \
        DST[3] = ((kb_ + 6 >= 0) & ((unsigned)(q - kb_ - 6) < 256u)) ? s_[3] * 0.125f : -1e30f; \
    }

#define QKF_U(DST, HH, MM)                                                       \
    f32x4 DST; { QKCORE(HH, MM)                                                  \
        const int d_ = q - (k0s + (HH) * 32 + (MM) + lg * 8);                    \
        DST[0] = (d_ < 256)     ? s_[0] * 0.125f : -1e30f;                       \
        DST[1] = (d_ - 2 < 256) ? s_[1] * 0.125f : -1e30f;                       \
        DST[2] = (d_ - 4 < 256) ? s_[2] * 0.125f : -1e30f;                       \
        DST[3] = (d_ - 6 < 256) ? s_[3] * 0.125f : -1e30f;                       \
    }

#define QKF_L(DST, HH, MM)                                                       \
    f32x4 DST; { QKCORE(HH, MM)                                                  \
        const int d_ = q - (k0s + (HH) * 32 + (MM) + lg * 8);                    \
        DST[0] = (d_ >= 0)     ? s_[0] * 0.125f : -1e30f;                        \
        DST[1] = (d_ - 2 >= 0) ? s_[1] * 0.125f : -1e30f;                        \
        DST[2] = (d_ - 4 >= 0) ? s_[2] * 0.125f : -1e30f;                        \
        DST[3] = (d_ - 6 >= 0) ? s_[3] * 0.125f : -1e30f;                        \
    }

#define QKF_N(DST, HH, MM)                                                       \
    f32x4 DST; { QKCORE(HH, MM)                                                  \
        DST[0] = s_[0] * 0.125f; DST[1] = s_[1] * 0.125f;                        \
        DST[2] = s_[2] * 0.125f; DST[3] = s_[3] * 0.125f;                        \
    }

#define EXV(S_) {                                                                \
        S_[0] = __expf(S_[0] - mnew); S_[1] = __expf(S_[1] - mnew);              \
        S_[2] = __expf(S_[2] - mnew); S_[3] = __expf(S_[3] - mnew);              \
        rs += (S_[0] + S_[1]) + (S_[2] + S_[3]); }

#define PVF(NT, HH, PB) {                                                        \
        bf16x8 va_ = *(const bf16x8*)(vbase + ((NT) * 16 + lr) * 128 +           \
                                      ((((HH) * 4 + lg) ^ swv) << 4));           \
        o##NT = MFMA16(va_, PB, o##NT); }

#define TILEBODY(QKM) {                                                          \
        QKM(sA, 0, 0) QKM(sB, 0, 1) QKM(sC, 1, 0) QKM(sD, 1, 1)                  \
        float tm = fmaxf(fmaxf(fmaxf(sA[0], sA[1]), fmaxf(sA[2], sA[3])),        \
                         fmaxf(fmaxf(sB[0], sB[1]), fmaxf(sB[2], sB[3])));       \
        tm = fmaxf(tm, fmaxf(fmaxf(fmaxf(sC[0], sC[1]), fmaxf(sC[2], sC[3])),    \
                             fmaxf(fmaxf(sD[0], sD[1]), fmaxf(sD[2], sD[3]))));  \
        tm = fmaxf(tm, __shfl_xor(tm, 16));                                      \
        tm = fmaxf(tm, __shfl_xor(tm, 32));                                      \
        const float mnew = fmaxf(mrun, tm);                                      \
        const float alpha = __expf(mrun - mnew);                                 \
        mrun = mnew;                                                             \
        float rs = 0.f;                                                          \
        EXV(sA) EXV(sB) EXV(sC) EXV(sD)                                          \
        rs += __shfl_xor(rs, 16);                                                \
        rs += __shfl_xor(rs, 32);                                                \
        lsum = lsum * alpha + rs;                                                \
        o0[0] *= alpha; o0[1] *= alpha; o0[2] *= alpha; o0[3] *= alpha;          \
        o1[0] *= alpha; o1[1] *= alpha; o1[2] *= alpha; o1[3] *= alpha;          \
        o2[0] *= alpha; o2[1] *= alpha; o2[2] *= alpha; o2[3] *= alpha;          \
        o3[0] *= alpha; o3[1] *= alpha; o3[2] *= alpha; o3[3] *= alpha;          \
        bf16x8 pb0, pb1;                                                         \
        pb0[0] = (bf16_t)sA[0]; pb0[1] = (bf16_t)sA[1]; pb0[2] = (bf16_t)sA[2]; pb0[3] = (bf16_t)sA[3]; \
        pb0[4] = (bf16_t)sB[0]; pb0[5] = (bf16_t)sB[1]; pb0[6] = (bf16_t)sB[2]; pb0[7] = (bf16_t)sB[3]; \
        pb1[0] = (bf16_t)sC[0]; pb1[1] = (bf16_t)sC[1]; pb1[2] = (bf16_t)sC[2]; pb1[3] = (bf16_t)sC[3]; \
        pb1[4] = (bf16_t)sD[0]; pb1[5] = (bf16_t)sD[1]; pb1[6] = (bf16_t)sD[2]; pb1[7] = (bf16_t)sD[3]; \
        PVF(0, 0, pb0) PVF(1, 0, pb0) PVF(2, 0, pb0) PVF(3, 0, pb0)              \
        PVF(0, 1, pb1) PVF(1, 1, pb1) PVF(2, 1, pb1) PVF(3, 1, pb1)              \
    }

#define SETT(U) kbase = (const char*)kld + (U) * 8192;                           \
                vbase = (const char*)vld + (U) * 8192;                           \
                k0s = (tb + (U)) * 64;

    if (qt >= 4) {
        SETT(0) TILEBODY(QKF_U)
        SETT(1) TILEBODY(QKF_N)
        SETT(2) TILEBODY(QKF_N)
        SETT(3) TILEBODY(QKF_N)
        SETT(4) TILEBODY(QKF_L)
    } else {
#pragma unroll
        for (int u = 0; u < 5; ++u) {
            SETT(u) TILEBODY(QKF_F)
        }
    }
#undef SETT
#undef TILEBODY
#undef QKF_F
#undef QKF_U
#undef QKF_L
#undef QKF_N
#undef QKCORE
#undef EXV
#undef PVF

    const float rinv = 1.0f / lsum;
    bf16_t* aor = Ao + ((long)(b * 2048) + q) * 1024 + h * 64;
#define EPI(NT, OA_) {                                                           \
        bf16x4 ov_;                                                             \
        ov_[0] = (bf16_t)(OA_[0] * rinv); ov_[1] = (bf16_t)(OA_[1] * rinv);      \
        ov_[2] = (bf16_t)(OA_[2] * rinv); ov_[3] = (bf16_t)(OA_[3] * rinv);      \
        *(bf16x4*)(aor + (NT) * 16 + lg * 4) = ov_; }
    EPI(0, o0) EPI(1, o1) EPI(2, o2) EPI(3, o3)
#undef EPI
}

// ---------------------------------------------------------------------------
extern "C" void kernel_launch(void* const* d_in, const int* in_sizes, int n_in,
                              void* d_out, int out_size, void* d_ws, size_t ws_size,
                              hipStream_t stream) {
    (void)in_sizes; (void)n_in; (void)out_size; (void)ws_size;
    const float* x    = (const float*)d_in[0];
    const float* fcos = (const float*)d_in[1];
    const float* fsin = (const float*)d_in[2];
    const float* wq   = (const float*)d_in[3];
    const float* wk   = (const float*)d_in[4];
    const float* wv   = (const float*)d_in[5];
    const float* wo   = (const float*)d_in[6];
    float* out = (float*)d_out;

    char* ws = (char*)d_ws;
    // layout (bytes): xbf 16MB @0 | wqkv 6MB @16M | wobf 2MB @22M |
    //                 vtmp 16MB @24M | qbuf 16MB @40M | kbuf 16MB @72M |
    //                 vtb 16MB @88M.   aob reuses xbf (dead after gemm192).
    bf16_t* xbf  = (bf16_t*)(ws);
    bf16_t* wqkv = (bf16_t*)(ws + 16777216);
    bf16_t* wobf = (bf16_t*)(ws + 23068672);
    bf16_t* vtmp = (bf16_t*)(ws + 25165824);
    bf16_t* qbuf = (bf16_t*)(ws + 41943040);
    bf16_t* kbuf = (bf16_t*)(ws + 75497472);
    bf16_t* vtb  = (bf16_t*)(ws + 92274688);
    bf16_t* aob  = xbf;   // xbf dead after gemm192 (rope fused away)

    cvt_all<<<6144, 256, 0, stream>>>(x, wq, wk, wv, wo, xbf, wqkv, wobf);

    // QKV + fused RoPE/layout: grid (3072/192, 8192/256) = (16,32) = 512 blocks
    gemm192_qkv<<<dim3(16, 32), 512, 0, stream>>>(xbf, wqkv, fcos, fsin,
                                                  qbuf, kbuf, vtmp,
                                                  8192, 3072, 1024);
    vt_transpose<<<2048, 256, 0, stream>>>(vtmp, vtb);
    attn_win4<<<2048, 256, 0, stream>>>(qbuf, kbuf, vtb, aob);
    // O-proj: grid (8, 32) = 256 blocks = 1 exact round
    gemm256<float><<<dim3(8, 32), 512, 0, stream>>>(aob, wobf, out, 8192, 1024, 1024);
}

// Round 8
// 126.885 us; speedup vs baseline: 1.2109x; 1.0253x over previous
//
#include <hip/hip_runtime.h>
#include <hip/hip_bf16.h>

// ---------------------------------------------------------------------------
// Sliding-window attention (B=4,S=2048,D=1024,H=16,HD=64,W=256) on gfx950.
// Pipeline: cvt(all + RoPE-table transpose) -> GEMM(QKV, 256x192 8-phase,
//           FUSED epilogue: RoPE'd Q/K to [bh][s][64] + V to VT via in-LDS
//           transpose) -> flash window attention (mask-specialized) ->
//           GEMM(O-proj, 256x128 3-buffer).
// ---------------------------------------------------------------------------

typedef __bf16 bf16_t;
typedef __attribute__((ext_vector_type(8))) __bf16 bf16x8;
typedef __attribute__((ext_vector_type(4))) __bf16 bf16x4;
typedef __attribute__((ext_vector_type(4))) float f32x4;

#define MFMA16(a, b, c) __builtin_amdgcn_mfma_f32_16x16x32_bf16((a), (b), (c), 0, 0, 0)

// async global->LDS, 16 bytes per lane. LDS dest is wave-uniform base + lane*16.
__device__ __forceinline__ void async16(const void* g, void* l) {
    __builtin_amdgcn_global_load_lds(
        (const __attribute__((address_space(1))) unsigned int*)g,
        (__attribute__((address_space(3))) unsigned int*)l, 16, 0, 0);
}

#define BAR() do { asm volatile("" ::: "memory"); __builtin_amdgcn_s_barrier(); \
                   asm volatile("" ::: "memory"); } while (0)
#define VMC(N) asm volatile("s_waitcnt vmcnt(" #N ")" ::: "memory")
#define LGKM0() asm volatile("s_waitcnt lgkmcnt(0)" ::: "memory")

// ---------------------------------------------------------------------------
// Fused f32 -> bf16 convert for all 5 tensors + RoPE table transpose.
// Blocks [0,4096): x; [4096,4608): wq; [4608,5120): wk; [5120,5632): wv;
// [5632,6144): wo; [6144,6176): table transpose (p = blk-6144).
// ---------------------------------------------------------------------------
__global__ __launch_bounds__(256) void cvt_all(const float* __restrict__ x,
                                               const float* __restrict__ wq,
                                               const float* __restrict__ wk,
                                               const float* __restrict__ wv,
                                               const float* __restrict__ wo,
                                               const float* __restrict__ fcos,
                                               const float* __restrict__ fsin,
                                               bf16_t* __restrict__ xbf,
                                               bf16_t* __restrict__ wqkv,
                                               bf16_t* __restrict__ wobf,
                                               float* __restrict__ fcosT,
                                               float* __restrict__ fsinT) {
    const int blk = blockIdx.x;
    if (blk >= 6144) {
        // transpose: out[p][s] = in[s][p]   (32 x 2048 f32 each)
        const int p = blk - 6144;
        for (int s = threadIdx.x; s < 2048; s += 256) {
            fcosT[p * 2048 + s] = fcos[s * 32 + p];
            fsinT[p * 2048 + s] = fsin[s * 32 + p];
        }
        return;
    }
    const float* s;
    bf16_t* d;
    int base;
    if (blk < 4096)      { s = x;  d = xbf;            base = blk; }
    else if (blk < 4608) { s = wq; d = wqkv;           base = blk - 4096; }
    else if (blk < 5120) { s = wk; d = wqkv + 1048576; base = blk - 4608; }
    else if (blk < 5632) { s = wv; d = wqkv + 2097152; base = blk - 5120; }
    else                 { s = wo; d = wobf;           base = blk - 5632; }
    const int i = (base * 256 + threadIdx.x) * 8;
    float4 a = *(const float4*)(s + i);
    float4 b = *(const float4*)(s + i + 4);
    bf16x8 o;
    o[0] = (bf16_t)a.x; o[1] = (bf16_t)a.y; o[2] = (bf16_t)a.z; o[3] = (bf16_t)a.w;
    o[4] = (bf16_t)b.x; o[5] = (bf16_t)b.y; o[6] = (bf16_t)b.z; o[7] = (bf16_t)b.w;
    *(bf16x8*)(d + i) = o;
}

// ---------------------------------------------------------------------------
// 256x192 8-phase QKV GEMM with FUSED RoPE + layout epilogue.
// Main loop identical to R4/R6 (counted vmcnt, st_16x32 swizzle, 8 waves).
// Epilogue (per 16-col fragment; class = cbase>>10 is wave-uniform):
//   q/k: RoPE in-register (partner channel = __shfl_xor(v,1)); cos/sin from
//        TRANSPOSED tables (p2-major) -> float4 per 4 consecutive tokens;
//        store [bh][s][64].
//   v:   per-wave in-LDS transpose (As/Bs dead after last barrier; 128x18
//        bf16 scratch, pad 18 -> conflict-free reads), read back with the
//        within-8 key permutation (pos p holds key (p&~7)|rotl3(p&7)), store
//        bf16x8 to VT[bh][64][2048]; lanes {ch,ch+16,ch+32,ch+48} cover 64 B.
// Scratch safety: buf0 of As/Bs is free after the VMC(0)+BAR preceding the
// last tile (all waves' buf0 reads retired); regions are per-wave private;
// same-wave LDS RAW ordered by in-order DS + lgkmcnt(0) + memory clobbers.
// ---------------------------------------------------------------------------
__global__ __launch_bounds__(512, 1) __attribute__((amdgpu_waves_per_eu(2)))
void gemm192_qkv(const bf16_t* __restrict__ A, const bf16_t* __restrict__ Bw,
                 const float* __restrict__ fcosT, const float* __restrict__ fsinT,
                 bf16_t* __restrict__ Qo, bf16_t* __restrict__ Ko,
                 bf16_t* __restrict__ VT, int M, int N, int K) {
    __shared__ __attribute__((aligned(16))) bf16_t As[32768];   // 2 x 4u x 8KiB
    __shared__ __attribute__((aligned(16))) bf16_t Bs[24576];   // 2 x 3u x 8KiB
    const int tid = threadIdx.x;
    const int l = tid & 63, w = tid >> 6;
    const int lr = l & 15, lg = l >> 4;
    const int wr = w >> 2, wc = w & 3;          // 2M x 4N

    const int nwg = gridDim.x * gridDim.y;
    const int flat = blockIdx.y * gridDim.x + blockIdx.x;
    const int swz = (flat & 7) * (nwg >> 3) + (flat >> 3);
    const int bx = swz % gridDim.x, by = swz / gridDim.x;
    const long m0 = (long)by * 256, n0 = (long)bx * 192;
    const int NT = K >> 6;
    const int NI = NT >> 1;

    const int p  = w * 1024 + l * 16;
    const int pp = p ^ (((p >> 9) & 1) << 5);
    const int st = pp >> 10;
    const int rSt = (st >> 1) * 16 + ((pp >> 6) & 15);
    const int cSt = (st & 1) * 32 + ((pp >> 4) & 3) * 8;
    const bf16_t* aS = A  + (m0 + rSt) * K + cSt;
    const bf16_t* bS = Bw + (n0 + rSt) * K + cSt;
    const long uK = 64L * K;

    auto stageA = [&](int b, int u, int t) {
        async16(aS + (long)u * uK + (long)t * 64,
                (char*)As + b * 32768 + u * 8192 + w * 1024);
    };
    auto stageB = [&](int b, int u, int t) {
        async16(bS + (long)u * uK + (long)t * 64,
                (char*)Bs + b * 24576 + u * 8192 + w * 1024);
    };

    f32x4 acc[8][3] = {};
    bf16x8 afX[4], afY[4], bfX[3], bfY[3];
    const int swd = (lr & 8) << 2;

    auto loadAF = [&](int b, int mh, int ks, bf16x8 (&dst)[4]) {
#pragma unroll
        for (int mi = 0; mi < 4; ++mi) {
            const int off = (wr * 2 + mh) * 8192 + (mi * 2 + ks) * 1024 +
                            lr * 64 + lg * 16;
            dst[mi] = *(const bf16x8*)((const char*)As + b * 32768 + (off ^ swd));
        }
    };
    auto loadBF = [&](int b, int ks, bf16x8 (&dst)[3]) {
#pragma unroll
        for (int nj = 0; nj < 3; ++nj) {
            const int rg = wc * 48 + nj * 16 + lr;
            const int off = (rg >> 6) * 8192 + (((rg >> 4) & 3) * 2 + ks) * 1024 +
                            lr * 64 + lg * 16;
            dst[nj] = *(const bf16x8*)((const char*)Bs + b * 24576 + (off ^ swd));
        }
    };

#define QMM(MH, AF, BF) do {                                                   \
    __builtin_amdgcn_s_setprio(1);                                             \
    _Pragma("unroll")                                                          \
    for (int mi = 0; mi < 4; ++mi)                                             \
        _Pragma("unroll")                                                      \
        for (int nj = 0; nj < 3; ++nj)                                         \
            acc[(MH)*4+mi][nj] = MFMA16((AF)[mi], (BF)[nj], acc[(MH)*4+mi][nj]); \
    __builtin_amdgcn_s_setprio(0);                                             \
} while (0)

    // ---- prologue ----
    stageA(0, 0, 0); stageA(0, 1, 0); stageA(0, 2, 0); stageA(0, 3, 0);
    stageB(0, 0, 0); stageB(0, 1, 0); stageB(0, 2, 0);
    stageB(1, 0, 1); stageB(1, 1, 1); stageB(1, 2, 1);
    VMC(3);
    BAR();

#pragma unroll 1
    for (int it = 0; it < NI - 1; ++it) {
        const int T = 2 * it;
        loadAF(0, 0, 0, afX); loadBF(0, 0, bfX);
        stageA(1, 0, T + 1); stageA(1, 1, T + 1);
        BAR(); QMM(0, afX, bfX); BAR();
        loadAF(0, 1, 0, afY);
        stageA(1, 2, T + 1); stageA(1, 3, T + 1);
        BAR(); QMM(1, afY, bfX); BAR();
        loadAF(0, 0, 1, afX); loadBF(0, 1, bfY);
        BAR(); QMM(0, afX, bfY); BAR();
        loadAF(0, 1, 1, afY);
        stageB(0, 0, T + 2);
        BAR(); QMM(1, afY, bfY); VMC(1); BAR();
        loadAF(1, 0, 0, afX); loadBF(1, 0, bfX);
        stageB(0, 1, T + 2); stageB(0, 2, T + 2);
        BAR(); QMM(0, afX, bfX); BAR();
        loadAF(1, 1, 0, afY);
        stageA(0, 0, T + 2); stageA(0, 1, T + 2);
        BAR(); QMM(1, afY, bfX); BAR();
        loadAF(1, 0, 1, afX); loadBF(1, 1, bfY);
        stageA(0, 2, T + 2); stageA(0, 3, T + 2);
        BAR(); QMM(0, afX, bfY); BAR();
        loadAF(1, 1, 1, afY);
        stageB(1, 0, T + 3); stageB(1, 1, T + 3); stageB(1, 2, T + 3);
        BAR(); QMM(1, afY, bfY); VMC(3); BAR();
    }

    // ---- final iteration (tiles NT-2 buf0, NT-1 buf1) ----
    {
        loadAF(0, 0, 0, afX); loadBF(0, 0, bfX);
        stageA(1, 0, NT - 1); stageA(1, 1, NT - 1);
        BAR(); QMM(0, afX, bfX); BAR();
        loadAF(0, 1, 0, afY);
        stageA(1, 2, NT - 1); stageA(1, 3, NT - 1);
        BAR(); QMM(1, afY, bfX); BAR();
        loadAF(0, 0, 1, afX); loadBF(0, 1, bfY);
        BAR(); QMM(0, afX, bfY); BAR();
        loadAF(0, 1, 1, afY);
        BAR(); QMM(1, afY, bfY);
        VMC(0); BAR();                 // <- after this, buf0 of As/Bs is free
        loadAF(1, 0, 0, afX); loadBF(1, 0, bfX);
        QMM(0, afX, bfX);
        loadAF(1, 1, 0, afY);
        QMM(1, afY, bfX);
        loadAF(1, 0, 1, afX); loadBF(1, 1, bfY);
        QMM(0, afX, bfY);
        loadAF(1, 1, 1, afY);
        QMM(1, afY, bfY);
    }
#undef QMM

    // ---- FUSED epilogue ----
    // per-wave private scratch in buf0 (free): waves 0-5 in As, 6-7 in Bs.
    bf16_t* scr = (w < 6) ? (bf16_t*)((char*)As + w * 4608)
                          : (bf16_t*)((char*)Bs + (w - 6) * 4608);
    asm volatile("" ::: "memory");

#pragma unroll
    for (int nj = 0; nj < 3; ++nj) {
        const int cbase = (int)n0 + wc * 48 + nj * 16;   // multiple of 16
        const int cls = cbase >> 10;                     // 0=q,1=k,2=v
        if (cls == 2) {
            // ---- V: LDS transpose (128 tok x 16 ch, pad to 18) ----
#pragma unroll
            for (int ai = 0; ai < 8; ++ai)
#pragma unroll
                for (int j = 0; j < 4; ++j)
                    scr[(ai * 16 + lg * 4 + j) * 18 + lr] = (bf16_t)acc[ai][nj][j];
            LGKM0();
            asm volatile("" ::: "memory");
            const int ch = l & 15;                       // channel within frag
            const int g0 = l >> 4;                       // token-group phase
            const int d16 = cbase - 2048 + ch;
            const int hh = d16 >> 6, dd = d16 & 63;
            const long T0 = m0 + wr * 128;
            const int bb = (int)(T0 >> 11);
            const int s0 = (int)(T0 & 2047);
            bf16_t* vrow = VT + ((long)((bb * 16 + hh) * 64 + dd) * 2048) + s0;
#pragma unroll
            for (int qq = 0; qq < 4; ++qq) {
                const int grp = g0 + qq * 4;             // 0..15 (8-token group)
                bf16x8 o;
#pragma unroll
                for (int j = 0; j < 8; ++j) {
                    const int f = ((j & 3) << 1) | (j >> 2);  // pos j holds key f
                    o[j] = scr[(grp * 8 + f) * 18 + ch];
                }
                *(bf16x8*)(vrow + grp * 8) = o;
            }
            LGKM0();                   // scratch reusable by next V fragment
            asm volatile("" ::: "memory");
        } else {
            // ---- Q/K: in-register RoPE, transposed tables ----
            const int c = cbase + lr;
            const int dd = c & 63;
            const int p2 = dd >> 1;
            const int hh = (c >> 6) & 15;
            const float sgn = (lr & 1) ? 1.f : -1.f;
            bf16_t* qk = (cls == 0) ? Qo : Ko;
            const float* cT = fcosT + p2 * 2048;
            const float* sT = fsinT + p2 * 2048;
#pragma unroll
            for (int ai = 0; ai < 8; ++ai) {
                const long t0 = m0 + wr * 128 + ai * 16 + lg * 4;
                const int s0 = (int)(t0 & 2047);
                const int bb = (int)(t0 >> 11);
                const float4 cc = *(const float4*)(cT + s0);
                const float4 ss = *(const float4*)(sT + s0);
                bf16_t* row = qk + ((long)(bb * 16 + hh) * 2048 + s0) * 64 + dd;
                const float v0 = acc[ai][nj][0], pv0 = __shfl_xor(acc[ai][nj][0], 1);
                const float v1 = acc[ai][nj][1], pv1 = __shfl_xor(acc[ai][nj][1], 1);
                const float v2 = acc[ai][nj][2], pv2 = __shfl_xor(acc[ai][nj][2], 1);
                const float v3 = acc[ai][nj][3], pv3 = __shfl_xor(acc[ai][nj][3], 1);
                row[0]       = (bf16_t)(v0 * cc.x + sgn * (pv0 * ss.x));
                row[64]      = (bf16_t)(v1 * cc.y + sgn * (pv1 * ss.y));
                row[128]     = (bf16_t)(v2 * cc.z + sgn * (pv2 * ss.z));
                row[192]     = (bf16_t)(v3 * cc.w + sgn * (pv3 * ss.w));
            }
        }
    }
}

// ---------------------------------------------------------------------------
// 256x128 GEMM (O-proj: N=1024 -> 256 blocks = 1 exact round).
// Triple-buffered deep prefetch, counted vmcnt (R3/R4 version).
// ---------------------------------------------------------------------------
template <typename OUT>
__global__ __launch_bounds__(512, 2) void gemm256(const bf16_t* __restrict__ A,
                                                  const bf16_t* __restrict__ Bw,
                                                  OUT* __restrict__ C,
                                                  int M, int N, int K) {
    __shared__ __attribute__((aligned(16))) bf16_t As[49152];   // 3 x 2 x 128x64
    __shared__ __attribute__((aligned(16))) bf16_t Bs[24576];   // 3 x 128x64
    const int tid = threadIdx.x;
    const int l = tid & 63, w = tid >> 6;
    const int lr = l & 15, lg = l >> 4;
    const int wr = w >> 1, wc = w & 1;

    const int nwg = gridDim.x * gridDim.y;
    const int flat = blockIdx.y * gridDim.x + blockIdx.x;
    const int swz = (flat & 7) * (nwg >> 3) + (flat >> 3);
    const int bx = swz % gridDim.x, by = swz / gridDim.x;
    const long m0 = (long)by * 256, n0 = (long)bx * 128;
    const int NT = K >> 6;

    int rS[2], cS[2];
#pragma unroll
    for (int i = 0; i < 2; ++i) {
        const int p  = i * 8192 + w * 1024 + l * 16;
        const int pp = p ^ (((p >> 9) & 1) << 5);
        const int st = pp >> 10;
        rS[i] = (st >> 1) * 16 + ((pp >> 6) & 15);
        cS[i] = (st & 1) * 32 + ((pp >> 4) & 3) * 8;
    }
    const bf16_t* aSrc0 = A  + (m0 + rS[0]) * K + cS[0];
    const bf16_t* aSrc1 = A  + (m0 + rS[1]) * K + cS[1];
    const bf16_t* bSrc0 = Bw + (n0 + rS[0]) * K + cS[0];
    const bf16_t* bSrc1 = Bw + (n0 + rS[1]) * K + cS[1];
    const long hK = 128L * K;

    auto stageA = [&](int b, int h, int t) {
        char* d = (char*)As + b * 32768 + h * 16384 + w * 1024;
        const long o = (long)h * hK + (long)t * 64;
        async16(aSrc0 + o, d);
        async16(aSrc1 + o, d + 8192);
    };
    auto stageB = [&](int b, int t) {
        char* d = (char*)Bs + b * 16384 + w * 1024;
        const long o = (long)t * 64;
        async16(bSrc0 + o, d);
        async16(bSrc1 + o, d + 8192);
    };

    f32x4 acc[4][4] = {};
    bf16x8 af[4][2], blo[2][2], bhi[2][2];
    const int swd = (lr & 8) << 2;

    auto loadA = [&](int b) {
#pragma unroll
        for (int mi = 0; mi < 4; ++mi)
#pragma unroll
            for (int ks = 0; ks < 2; ++ks) {
                const int ra = (wr & 1) * 64 + mi * 16 + lr;
                const int off = ((ra >> 4) * 2 + ks) * 1024 + (ra & 15) * 64 + lg * 16;
                af[mi][ks] = *(const bf16x8*)((const char*)As + b * 32768 +
                                              (wr >> 1) * 16384 + (off ^ swd));
            }
    };
    auto loadB = [&](int b, int nh, bf16x8 (&dst)[2][2]) {
#pragma unroll
        for (int nj = 0; nj < 2; ++nj)
#pragma unroll
            for (int ks = 0; ks < 2; ++ks) {
                const int rb = wc * 64 + (nh * 2 + nj) * 16 + lr;
                const int off = ((rb >> 4) * 2 + ks) * 1024 + (rb & 15) * 64 + lg * 16;
                dst[nj][ks] = *(const bf16x8*)((const char*)Bs + b * 16384 +
                                               (off ^ swd));
            }
    };

#define QMM(NH, BF) do {                                                       \
    __builtin_amdgcn_s_setprio(1);                                             \
    _Pragma("unroll")                                                          \
    for (int mi = 0; mi < 4; ++mi) {                                           \
        acc[mi][(NH)*2]   = MFMA16(af[mi][0], (BF)[0][0], acc[mi][(NH)*2]);    \
        acc[mi][(NH)*2]   = MFMA16(af[mi][1], (BF)[0][1], acc[mi][(NH)*2]);    \
        acc[mi][(NH)*2+1] = MFMA16(af[mi][0], (BF)[1][0], acc[mi][(NH)*2+1]);  \
        acc[mi][(NH)*2+1] = MFMA16(af[mi][1], (BF)[1][1], acc[mi][(NH)*2+1]);  \
    }                                                                          \
    __builtin_amdgcn_s_setprio(0);                                             \
} while (0)

    stageA(0, 0, 0); stageA(0, 1, 0); stageB(0, 0);
    stageA(1, 0, 1); stageA(1, 1, 1); stageB(1, 1);
    VMC(6);
    BAR();

    int bc = 0;
#pragma unroll 1
    for (int t = 0; t < NT - 2; ++t) {
        const int bn = (bc + 2 >= 3) ? bc - 1 : bc + 2;
        loadA(bc); loadB(bc, 0, blo); stageA(bn, 0, t + 2); stageA(bn, 1, t + 2);
        BAR(); QMM(0, blo); BAR();
        loadB(bc, 1, bhi); stageB(bn, t + 2);
        BAR(); QMM(1, bhi);
        if (t < NT - 3) { VMC(6); } else { VMC(0); }
        BAR();
        bc = (bc + 1 >= 3) ? 0 : bc + 1;
    }
    {
        loadA(bc); loadB(bc, 0, blo);
        QMM(0, blo);
        loadB(bc, 1, bhi);
        QMM(1, bhi);
        const int b2 = (bc + 1 >= 3) ? 0 : bc + 1;
        loadA(b2); loadB(b2, 0, blo);
        QMM(0, blo);
        loadB(b2, 1, bhi);
        QMM(1, bhi);
    }
#undef QMM

#pragma unroll
    for (int mi = 0; mi < 4; ++mi)
#pragma unroll
        for (int ni = 0; ni < 4; ++ni)
#pragma unroll
            for (int j = 0; j < 4; ++j) {
                long r = m0 + wr * 64 + mi * 16 + lg * 4 + j;
                long c = n0 + wc * 64 + ni * 16 + lr;
                C[r * N + c] = (OUT)acc[mi][ni][j];
            }
}

// ---------------------------------------------------------------------------
// Sliding-window attention v5 (R6): whole K/V window staged to LDS up front,
// online softmax per 64-key tile, swapped QK^T, mask specialization for
// qt>=4 (u=0 upper-only, u=1..3 no mask, u=4 lower-only).
// ---------------------------------------------------------------------------
__global__ __launch_bounds__(256, 2) void attn_win4(const bf16_t* __restrict__ Q,
                                                    const bf16_t* __restrict__ Kb,
                                                    const bf16_t* __restrict__ VT,
                                                    bf16_t* __restrict__ Ao) {
    __shared__ __attribute__((aligned(16))) bf16_t kld[5 * 4096];
    __shared__ __attribute__((aligned(16))) bf16_t vld[5 * 4096];
    const int raw = blockIdx.x;
    const int mswz = ((raw & 7) << 8) | (raw >> 3);
    const int qt = mswz & 31, bh = mswz >> 5;
    const int h = bh & 15, b = bh >> 4;
    const int l = threadIdx.x & 63, w = threadIdx.x >> 6;
    const int lr = l & 15, lg = l >> 4;
    const int q0 = qt * 64 + w * 16;
    const int q = q0 + lr;
    const int tb = qt - 4;

    const bf16_t* Qp = Q + (long)bh * 2048 * 64;
    const bf16_t* Kp = Kb + (long)bh * 2048 * 64;
    const bf16_t* Vp = VT + (long)bh * 64 * 2048;

#pragma unroll
    for (int u = 0; u < 5; ++u) {
        const int kt = tb + u;
        const int kt64 = (kt < 0 ? 0 : kt) * 64;
#pragma unroll
        for (int part = 0; part < 2; ++part) {
            const int seg = w * 2 + part;
            const int r = seg * 8 + (l >> 3);
            const int sc = (l & 7) ^ ((r >> 1) & 7);
            async16(Kp + (long)(kt64 + r) * 64 + sc * 8,
                    (char*)kld + u * 8192 + seg * 1024);
            async16(Vp + (long)r * 2048 + kt64 + sc * 8,
                    (char*)vld + u * 8192 + seg * 1024);
        }
    }

    const bf16x8 qb0 = *(const bf16x8*)&Qp[q * 64 + lg * 8];
    const bf16x8 qb1 = *(const bf16x8*)&Qp[q * 64 + 32 + lg * 8];

    __syncthreads();

    float mrun = -1000.f, lsum = 0.f;
    f32x4 o0 = {0.f, 0.f, 0.f, 0.f}, o1 = {0.f, 0.f, 0.f, 0.f};
    f32x4 o2 = {0.f, 0.f, 0.f, 0.f}, o3 = {0.f, 0.f, 0.f, 0.f};
    const int swv = (lr >> 1) & 7;

    const char* kbase;
    const char* vbase;
    int k0s;

#define QKCORE(HH, MM)                                                           \
        const int row_ = (HH) * 32 + 2 * lr + (MM);                              \
        const int sw_ = (row_ >> 1) & 7;                                         \
        bf16x8 k0_ = *(const bf16x8*)(kbase + row_ * 128 + ((lg ^ sw_) << 4));   \
        bf16x8 k1_ = *(const bf16x8*)(kbase + row_ * 128 + (((4 + lg) ^ sw_) << 4)); \
        f32x4 s_ = {0.f, 0.f, 0.f, 0.f};                                         \
        s_ = MFMA16(k0_, qb0, s_);                                               \
        s_ = MFMA16(k1_, qb1, s_);

#define QKF_F(DST, HH, MM)                                                       \
    f32x4 DST; { QKCORE(HH, MM)                                                  \
        const int kb_ = k0s + (HH) * 32 + (MM) + lg * 8;                         \
        DST[0] = ((kb_ >= 0) & ((unsigned)(q - kb_) < 256u))         ? s_[0] * 0.125f : -1e30f; \
        DST[1] = ((kb_ + 2 >= 0) & ((unsigned)(q - kb_ - 2) < 256u)) ? s_[1] * 0.125f : -1e30f; \
        DST[2] = ((kb_ + 4 >= 0) & ((unsigned)(q - kb_ - 4) < 256u)) ? s_[2] * 0.125f : -1e30f; \
        DST[3] = ((kb_ + 6 >= 0) & ((unsigned)(q - kb_ - 6) < 256u)) ? s_[3] * 0.125f : -1e30f; \
    }

#define QKF_U(DST, HH, MM)                                                       \
    f32x4 DST; { QKCORE(HH, MM)                                                  \
        const int d_ = q - (k0s + (HH) * 32 + (MM) + lg * 8);                    \
        DST[0] = (d_ < 256)     ? s_[0] * 0.125f : -1e30f;                       \
        DST[1] = (d_ - 2 < 256) ? s_[1] * 0.125f : -1e30f;                       \
        DST[2] = (d_ - 4 < 256) ? s_[2] * 0.125f : -1e30f;                       \
        DST[3] = (d_ - 6 < 256) ? s_[3] * 0.125f : -1e30f;                       \
    }

#define QKF_L(DST, HH, MM)                                                       \
    f32x4 DST; { QKCORE(HH, MM)                                                  \
        const int d_ = q - (k0s + (HH) * 32 + (MM) + lg * 8);                    \
        DST[0] = (d_ >= 0)     ? s_[0] * 0.125f : -1e30f;                        \
        DST[1] = (d_ - 2 >= 0) ? s_[1] * 0.125f : -1e30f;                        \
        DST[2] = (d_ - 4 >= 0) ? s_[2] * 0.125f : -1e30f;                        \
        DST[3] = (d_ - 6 >= 0) ? s_[3] * 0.125f : -1e30f;                        \
    }

#define QKF_N(DST, HH, MM)                                                       \
    f32x4 DST; { QKCORE(HH, MM)                                                  \
        DST[0] = s_[0] * 0.125f; DST[1] = s_[1] * 0.125f;                        \
        DST[2] = s_[2] * 0.125f; DST[3] = s_[3] * 0.125f;                        \
    }

#define EXV(S_) {                                                                \
        S_[0] = __expf(S_[0] - mnew); S_[1] = __expf(S_[1] - mnew);              \
        S_[2] = __expf(S_[2] - mnew); S_[3] = __expf(S_[3] - mnew);              \
        rs += (S_[0] + S_[1]) + (S_[2] + S_[3]); }

#define PVF(NT, HH, PB) {                                                        \
        bf16x8 va_ = *(const bf16x8*)(vbase + ((NT) * 16 + lr) * 128 +           \
                                      ((((HH) * 4 + lg) ^ swv) << 4));           \
        o##NT = MFMA16(va_, PB, o##NT); }

#define TILEBODY(QKM) {                                                          \
        QKM(sA, 0, 0) QKM(sB, 0, 1) QKM(sC, 1, 0) QKM(sD, 1, 1)                  \
        float tm = fmaxf(fmaxf(fmaxf(sA[0], sA[1]), fmaxf(sA[2], sA[3])),        \
                         fmaxf(fmaxf(sB[0], sB[1]), fmaxf(sB[2], sB[3])));       \
        tm = fmaxf(tm, fmaxf(fmaxf(fmaxf(sC[0], sC[1]), fmaxf(sC[2], sC[3])),    \
                             fmaxf(fmaxf(sD[0], sD[1]), fmaxf(sD[2], sD[3]))));  \
        tm = fmaxf(tm, __shfl_xor(tm, 16));                                      \
        tm = fmaxf(tm, __shfl_xor(tm, 32));                                      \
        const float mnew = fmaxf(mrun, tm);                                      \
        const float alpha = __expf(mrun - mnew);                                 \
        mrun = mnew;                                                             \
        float rs = 0.f;                                                          \
        EXV(sA) EXV(sB) EXV(sC) EXV(sD)                                          \
        rs += __shfl_xor(rs, 16);                                                \
        rs += __shfl_xor(rs, 32);                                                \
        lsum = lsum * alpha + rs;                                                \
        o0[0] *= alpha; o0[1] *= alpha; o0[2] *= alpha; o0[3] *= alpha;          \
        o1[0] *= alpha; o1[1] *= alpha; o1[2] *= alpha; o1[3] *= alpha;          \
        o2[0] *= alpha; o2[1] *= alpha; o2[2] *= alpha; o2[3] *= alpha;          \
        o3[0] *= alpha; o3[1] *= alpha; o3[2] *= alpha; o3[3] *= alpha;          \
        bf16x8 pb0, pb1;                                                         \
        pb0[0] = (bf16_t)sA[0]; pb0[1] = (bf16_t)sA[1]; pb0[2] = (bf16_t)sA[2]; pb0[3] = (bf16_t)sA[3]; \
        pb0[4] = (bf16_t)sB[0]; pb0[5] = (bf16_t)sB[1]; pb0[6] = (bf16_t)sB[2]; pb0[7] = (bf16_t)sB[3]; \
        pb1[0] = (bf16_t)sC[0]; pb1[1] = (bf16_t)sC[1]; pb1[2] = (bf16_t)sC[2]; pb1[3] = (bf16_t)sC[3]; \
        pb1[4] = (bf16_t)sD[0]; pb1[5] = (bf16_t)sD[1]; pb1[6] = (bf16_t)sD[2]; pb1[7] = (bf16_t)sD[3]; \
        PVF(0, 0, pb0) PVF(1, 0, pb0) PVF(2, 0, pb0) PVF(3, 0, pb0)              \
        PVF(0, 1, pb1) PVF(1, 1, pb1) PVF(2, 1, pb1) PVF(3, 1, pb1)              \
    }

#define SETT(U) kbase = (const char*)kld + (U) * 8192;                           \
                vbase = (const char*)vld + (U) * 8192;                           \
                k0s = (tb + (U)) * 64;

    if (qt >= 4) {
        SETT(0) TILEBODY(QKF_U)
        SETT(1) TILEBODY(QKF_N)
        SETT(2) TILEBODY(QKF_N)
        SETT(3) TILEBODY(QKF_N)
        SETT(4) TILEBODY(QKF_L)
    } else {
#pragma unroll
        for (int u = 0; u < 5; ++u) {
            SETT(u) TILEBODY(QKF_F)
        }
    }
#undef SETT
#undef TILEBODY
#undef QKF_F
#undef QKF_U
#undef QKF_L
#undef QKF_N
#undef QKCORE
#undef EXV
#undef PVF

    const float rinv = 1.0f / lsum;
    bf16_t* aor = Ao + ((long)(b * 2048) + q) * 1024 + h * 64;
#define EPI(NT, OA_) {                                                           \
        bf16x4 ov_;                                                             \
        ov_[0] = (bf16_t)(OA_[0] * rinv); ov_[1] = (bf16_t)(OA_[1] * rinv);      \
        ov_[2] = (bf16_t)(OA_[2] * rinv); ov_[3] = (bf16_t)(OA_[3] * rinv);      \
        *(bf16x4*)(aor + (NT) * 16 + lg * 4) = ov_; }
    EPI(0, o0) EPI(1, o1) EPI(2, o2) EPI(3, o3)
#undef EPI
}

// ---------------------------------------------------------------------------
extern "C" void kernel_launch(void* const* d_in, const int* in_sizes, int n_in,
                              void* d_out, int out_size, void* d_ws, size_t ws_size,
                              hipStream_t stream) {
    (void)in_sizes; (void)n_in; (void)out_size; (void)ws_size;
    const float* x    = (const float*)d_in[0];
    const float* fcos = (const float*)d_in[1];
    const float* fsin = (const float*)d_in[2];
    const float* wq   = (const float*)d_in[3];
    const float* wk   = (const float*)d_in[4];
    const float* wv   = (const float*)d_in[5];
    const float* wo   = (const float*)d_in[6];
    float* out = (float*)d_out;

    char* ws = (char*)d_ws;
    // layout (bytes): xbf 16MB @0 | wqkv 6MB @16M | wobf 2MB @22M |
    //                 fcosT 256KB @24M | fsinT 256KB | qbuf 16MB @40M |
    //                 kbuf 16MB @72M | vtb 16MB @88M. aob reuses xbf.
    bf16_t* xbf   = (bf16_t*)(ws);
    bf16_t* wqkv  = (bf16_t*)(ws + 16777216);
    bf16_t* wobf  = (bf16_t*)(ws + 23068672);
    float*  fcosT = (float*)(ws + 25165824);
    float*  fsinT = (float*)(ws + 25427968);
    bf16_t* qbuf  = (bf16_t*)(ws + 41943040);
    bf16_t* kbuf  = (bf16_t*)(ws + 75497472);
    bf16_t* vtb   = (bf16_t*)(ws + 92274688);
    bf16_t* aob   = xbf;   // xbf dead after gemm192_qkv

    cvt_all<<<6176, 256, 0, stream>>>(x, wq, wk, wv, wo, fcos, fsin,
                                      xbf, wqkv, wobf, fcosT, fsinT);

    // QKV + fused RoPE/layout/V-transpose: (16,32) = 512 blocks = 2 rounds
    gemm192_qkv<<<dim3(16, 32), 512, 0, stream>>>(xbf, wqkv, fcosT, fsinT,
                                                  qbuf, kbuf, vtb,
                                                  8192, 3072, 1024);
    attn_win4<<<2048, 256, 0, stream>>>(qbuf, kbuf, vtb, aob);
    // O-proj: grid (8, 32) = 256 blocks = 1 exact round
    gemm256<float><<<dim3(8, 32), 512, 0, stream>>>(aob, wobf, out, 8192, 1024, 1024);
}